// Round 5
// baseline (256.636 us; speedup 1.0000x reference)
//
#include <hip/hip_runtime.h>

#define NPTS 768
#define CCH  128
#define NM4  36    // 35 deg<=4 monomials in (d,u,v) + 1 pad
#define NM2  10    // deg<=2 monomials
#define TILE 128
#define NCHUNK 6   // one 128-tile of n per block
#define PAIR (NPTS*CCH)
#define NPOST 384  // k_post grid
#define LOG2E 1.4426950408889634f

typedef float f4 __attribute__((ext_vector_type(4)));

__device__ __forceinline__ float fast_exp2(float x) {
  return __builtin_amdgcn_exp2f(x);   // v_exp_f32 (base-2)
}

// ---- monomial index helpers (compile-time foldable under full unroll) ------
__device__ __forceinline__ int t4i(int a, int b, int c) {
  int t = 0;
  for (int aa = 0; aa < a; ++aa) t += (5 - aa) * (6 - aa) / 2;
  for (int bb = 0; bb < b; ++bb) t += (5 - a - bb);
  return t + c;
}
__device__ __forceinline__ int t2i(int a, int b, int c) {
  int t = 0;
  for (int aa = 0; aa < a; ++aa) t += (3 - aa) * (4 - aa) / 2;
  for (int bb = 0; bb < b; ++bb) t += (3 - a - bb);
  return t + c;
}

// ---------------------------------------------------------------------------
// k_pre (1 block, 256 thr): norms; layer1/2 polynomial fold; layer3 fold to
// A3mT/B3mT (36 x 128, transposed). Also zeroes the k_post accumulator+ticket.
// ---------------------------------------------------------------------------
__global__ __launch_bounds__(256) void k_pre(
    const float* __restrict__ x,
    const float* __restrict__ Wa1, const float* __restrict__ ba1,
    const float* __restrict__ Wb1, const float* __restrict__ bb1,
    const float* __restrict__ Wa2, const float* __restrict__ ba2,
    const float* __restrict__ Wb2, const float* __restrict__ bb2,
    const float* __restrict__ Wa3, const float* __restrict__ ba3,
    const float* __restrict__ Wb3, const float* __restrict__ bb3,
    float* __restrict__ norms,
    float* __restrict__ A3mT, float* __restrict__ B3mT,
    float* __restrict__ apart, unsigned int* __restrict__ ticket) {
  __shared__ float C1m[CCH][NM2];
  __shared__ float A2m[CCH][NM2];
  __shared__ float B2m[CCH][NM2];
  __shared__ float C2l[CCH][NM4];
  const int tid = threadIdx.x;

  // zero k_post scratch (stream-ordered before k_post)
  if (tid < NPOST) apart[tid] = 0.f;          // 3*128 accumulator
  if (tid == 0) *ticket = 0u;

  for (int i = tid; i < NPTS; i += 256) {
    float a = x[3*i], b = x[3*i+1], c = x[3*i+2];
    norms[i] = sqrtf(a*a + b*b + c*c);
  }
  if (tid < CCH) {
    const int c = tid;
    float La[4] = {Wa1[3*c], Wa1[3*c+1], Wa1[3*c+2], ba1[c]};
    float Lb[4] = {Wb1[3*c], Wb1[3*c+1], Wb1[3*c+2], bb1[c]};
    float acc[NM2];
    #pragma unroll
    for (int t = 0; t < NM2; ++t) acc[t] = 0.f;
    #pragma unroll
    for (int p = 0; p < 4; ++p)
      #pragma unroll
      for (int q = 0; q < 4; ++q) {
        const int ea = (p==0) + (q==0);
        const int eb = (p==1) + (q==1);
        const int ec = (p==2) + (q==2);
        acc[t2i(ea, eb, ec)] += La[p]*Lb[q];
      }
    #pragma unroll
    for (int t = 0; t < NM2; ++t) C1m[c][t] = acc[t];
  }
  __syncthreads();
  for (int idx = tid; idx < CCH*NM2; idx += 256) {
    const int c = idx / NM2, t = idx % NM2;
    float sa = 0.f, sb = 0.f;
    for (int k = 0; k < CCH; ++k) {
      const float v = C1m[k][t];
      sa += Wa2[c*CCH + k] * v;
      sb += Wb2[c*CCH + k] * v;
    }
    if (t == 0) { sa += ba2[c]; sb += bb2[c]; }
    A2m[c][t] = sa; B2m[c][t] = sb;
  }
  __syncthreads();
  if (tid < CCH) {
    const int c = tid;
    float acc[35];
    #pragma unroll
    for (int t = 0; t < 35; ++t) acc[t] = 0.f;
    #pragma unroll
    for (int a1 = 0; a1 <= 2; ++a1)
      #pragma unroll
      for (int b1 = 0; b1 <= 2; ++b1)
        #pragma unroll
        for (int c1 = 0; c1 <= 2; ++c1)
          if (a1 + b1 + c1 <= 2) {
            const float av = A2m[c][t2i(a1,b1,c1)];
            #pragma unroll
            for (int a2 = 0; a2 <= 2; ++a2)
              #pragma unroll
              for (int b2 = 0; b2 <= 2; ++b2)
                #pragma unroll
                for (int c2 = 0; c2 <= 2; ++c2)
                  if (a2 + b2 + c2 <= 2)
                    acc[t4i(a1+a2, b1+b2, c1+c2)] += av * B2m[c][t2i(a2,b2,c2)];
          }
    #pragma unroll
    for (int t = 0; t < 35; ++t) C2l[c][t] = acc[t];
    C2l[c][35] = 0.f;
  }
  __syncthreads();
  // layer-3 fold: threads 0-127 do A, 128-255 do B; each thread one channel.
  {
    const int half = tid >> 7;
    const int c = tid & 127;
    const float* W = half ? (Wb3 + c*CCH) : (Wa3 + c*CCH);
    float acc[NM4];
    #pragma unroll
    for (int j = 0; j < NM4; ++j) acc[j] = 0.f;
    for (int k = 0; k < CCH; ++k) {
      const float w = W[k];
      #pragma unroll
      for (int j = 0; j < NM4; ++j) acc[j] += w * C2l[k][j];
    }
    acc[0] += half ? bb3[c] : ba3[c];   // constant monomial
    float* dst = half ? B3mT : A3mT;
    for (int j = 0; j < NM4; ++j) dst[j*CCH + c] = acc[j];
  }
}

// ---------------------------------------------------------------------------
// k_main: block = (row m, n-chunk of 128). 128 threads = channels.
// Online softmax in log2 domain + x-weighted accumulators. Packed-f32 dots.
// ---------------------------------------------------------------------------
__global__ __launch_bounds__(128) void k_main(
    const float* __restrict__ x, const float* __restrict__ norms,
    const float* __restrict__ A3mT, const float* __restrict__ B3mT,
    float* __restrict__ Mp, float* __restrict__ Sp,
    float* __restrict__ A0p, float* __restrict__ A1p, float* __restrict__ A2p) {
  __shared__ __align__(16) float wlds[TILE][16];
  __shared__ __align__(16) float xt[TILE][4];
  const int c = threadIdx.x;
  const int m = blockIdx.x;
  const int chunk = blockIdx.y;

  const float u = norms[m];
  const float xm0 = x[3*m], xm1 = x[3*m+1], xm2 = x[3*m+2];

  // Build this thread's psi row (n = chunk*128 + c) into LDS.
  {
    const int n = chunk*TILE + c;
    const float v = norms[n];
    const float x0 = x[3*n], x1 = x[3*n+1], x2 = x[3*n+2];
    const float dot = xm0*x0 + xm1*x1 + xm2*x2;
    float d2 = u*u + v*v - 2.f*dot;
    float d  = (d2 > 0.f) ? sqrtf(d2) : 0.f;
    float dp[5], vp[5];
    dp[0] = 1.f; vp[0] = 1.f;
    #pragma unroll
    for (int i = 1; i < 5; ++i) { dp[i] = dp[i-1]*d; vp[i] = vp[i-1]*v; }
    float wv[16]; int t = 0;
    #pragma unroll
    for (int i = 0; i <= 4; ++i)
      #pragma unroll
      for (int j = 0; i + j <= 4; ++j) wv[t++] = dp[i]*vp[j];
    wv[15] = 0.f;
    float4* dst = (float4*)&wlds[c][0];
    dst[0] = make_float4(wv[0],  wv[1],  wv[2],  wv[3]);
    dst[1] = make_float4(wv[4],  wv[5],  wv[6],  wv[7]);
    dst[2] = make_float4(wv[8],  wv[9],  wv[10], wv[11]);
    dst[3] = make_float4(wv[12], wv[13], wv[14], wv[15]);
    *(float4*)&xt[c][0] = make_float4(x0, x1, x2, 0.f);
  }

  // Fold u-powers into per-channel coefficients; log2e folded into cA.
  float upow[5]; upow[0] = 1.f;
  #pragma unroll
  for (int b = 1; b < 5; ++b) upow[b] = upow[b-1]*u;
  float cA[16], cB[16];
  {
    int t = 0;
    #pragma unroll
    for (int i = 0; i <= 4; ++i)
      #pragma unroll
      for (int j = 0; i + j <= 4; ++j) {
        float sa = 0.f, sb = 0.f;
        #pragma unroll
        for (int b = 0; i + j + b <= 4; ++b) {
          const int t4 = t4i(i, b, j);   // (deg d, deg u, deg v)
          sa += A3mT[t4*CCH + c]*upow[b];
          sb += B3mT[t4*CCH + c]*upow[b];
        }
        cA[t] = sa*LOG2E; cB[t] = sb; ++t;
      }
    cA[15] = 0.f; cB[15] = 0.f;
  }
  f4 cAq[4], cBq[4];
  #pragma unroll
  for (int k = 0; k < 4; ++k) {
    cAq[k] = f4{cA[4*k], cA[4*k+1], cA[4*k+2], cA[4*k+3]};
    cBq[k] = f4{cB[4*k], cB[4*k+1], cB[4*k+2], cB[4*k+3]};
  }

  __syncthreads();

  float mrun = -INFINITY, srun = 0.f, a0 = 0.f, a1 = 0.f, a2 = 0.f;
  #pragma unroll 2
  for (int nn = 0; nn < TILE; ++nn) {
    const f4* pv = (const f4*)&wlds[nn][0];
    const f4 q0 = pv[0], q1 = pv[1], q2 = pv[2], q3 = pv[3];
    const f4 xq = *(const f4*)&xt[nn][0];
    f4 accA = cAq[0]*q0;
    f4 accB = cBq[0]*q0;
    accA += cAq[1]*q1; accB += cBq[1]*q1;
    accA += cAq[2]*q2; accB += cBq[2]*q2;
    accA += cAq[3]*q3; accB += cBq[3]*q3;
    const float la = (accA.x + accA.y) + (accA.z + accA.w);
    const float lb = (accB.x + accB.y) + (accB.z + accB.w);
    const float h2 = la * lb;                 // h * log2e
    const float mnew = fmaxf(mrun, h2);
    const float scale = fast_exp2(mrun - mnew);
    const float e = fast_exp2(h2 - mnew);
    srun = fmaf(srun, scale, e);
    a0 = fmaf(a0, scale, e*xq.x);
    a1 = fmaf(a1, scale, e*xq.y);
    a2 = fmaf(a2, scale, e*xq.z);
    mrun = mnew;
  }
  const int idx = chunk*PAIR + m*CCH + c;
  Mp[idx] = mrun; Sp[idx] = srun;
  A0p[idx] = a0; A1p[idx] = a1; A2p[idx] = a2;
}

// ---------------------------------------------------------------------------
// k_post: merge chunk partials per (m,c), normalize, atomicAdd the x-weighted
// aggregate into apart[3][128]; last block (ticket) does the Wf contraction.
// ---------------------------------------------------------------------------
__global__ __launch_bounds__(256) void k_post(
    const float* __restrict__ x,
    const float* __restrict__ Mp, const float* __restrict__ Sp,
    const float* __restrict__ A0p, const float* __restrict__ A1p,
    const float* __restrict__ A2p,
    const float* __restrict__ Wf,
    float* __restrict__ apart, unsigned int* __restrict__ ticket,
    float* __restrict__ out) {
  __shared__ float red[CCH][6];
  __shared__ bool last;
  const int tid = threadIdx.x;
  const int gid = blockIdx.x*256 + tid;   // (m,c) pair
  const int c = gid & 127;

  float mv[NCHUNK];
  float M = -INFINITY;
  #pragma unroll
  for (int ch = 0; ch < NCHUNK; ++ch) {
    mv[ch] = Mp[ch*PAIR + gid];
    M = fmaxf(M, mv[ch]);
  }
  float W = 0.f, g0 = 0.f, g1 = 0.f, g2 = 0.f;
  #pragma unroll
  for (int ch = 0; ch < NCHUNK; ++ch) {
    const float s = fast_exp2(mv[ch] - M);
    W  = fmaf(Sp [ch*PAIR + gid], s, W);
    g0 = fmaf(A0p[ch*PAIR + gid], s, g0);
    g1 = fmaf(A1p[ch*PAIR + gid], s, g1);
    g2 = fmaf(A2p[ch*PAIR + gid], s, g2);
  }
  const float inv = 1.f / W;
  atomicAdd(&apart[c],       g0*inv);
  atomicAdd(&apart[CCH + c], g1*inv);
  atomicAdd(&apart[2*CCH + c], g2*inv);

  __threadfence();
  __syncthreads();
  if (tid == 0) {
    const unsigned int old = atomicAdd(ticket, 1u);
    last = (old == NPOST - 1);
  }
  __syncthreads();
  if (!last) return;
  __threadfence();

  if (tid < CCH) {
    const int cc = tid;
    const float a0 = __hip_atomic_load(&apart[cc],        __ATOMIC_RELAXED, __HIP_MEMORY_SCOPE_AGENT);
    const float a1 = __hip_atomic_load(&apart[CCH + cc],  __ATOMIC_RELAXED, __HIP_MEMORY_SCOPE_AGENT);
    const float a2 = __hip_atomic_load(&apart[2*CCH + cc],__ATOMIC_RELAXED, __HIP_MEMORY_SCOPE_AGENT);
    const float w0 = Wf[cc], w1 = Wf[CCH + cc];
    red[cc][0] = w0*a0; red[cc][1] = w0*a1; red[cc][2] = w0*a2;
    red[cc][3] = w1*a0; red[cc][4] = w1*a1; red[cc][5] = w1*a2;
  }
  __syncthreads();
  if (tid < 6) {
    float s = 0.f;
    for (int k = 0; k < CCH; ++k) s += red[k][tid];
    out[3 + tid] = s;
  }
  if (tid < 3) out[tid] = x[tid];
}

// ---------------------------------------------------------------------------
extern "C" void kernel_launch(void* const* d_in, const int* in_sizes, int n_in,
                              void* d_out, int out_size, void* d_ws, size_t ws_size,
                              hipStream_t stream) {
  const float* x   = (const float*)d_in[0];
  const float* Wa1 = (const float*)d_in[1];
  const float* ba1 = (const float*)d_in[2];
  const float* Wb1 = (const float*)d_in[3];
  const float* bb1 = (const float*)d_in[4];
  const float* Wa2 = (const float*)d_in[5];
  const float* ba2 = (const float*)d_in[6];
  const float* Wb2 = (const float*)d_in[7];
  const float* bb2 = (const float*)d_in[8];
  const float* Wa3 = (const float*)d_in[9];
  const float* ba3 = (const float*)d_in[10];
  const float* Wb3 = (const float*)d_in[11];
  const float* bb3 = (const float*)d_in[12];
  const float* Wf  = (const float*)d_in[13];
  float* out = (float*)d_out;

  float* ws     = (float*)d_ws;
  float* norms  = ws;                      // 768
  float* A3mT   = norms + NPTS;            // 36*128
  float* B3mT   = A3mT  + NM4*CCH;         // 36*128
  float* Mp     = B3mT  + NM4*CCH;         // 6*98304
  float* Sp     = Mp    + NCHUNK*PAIR;     // 6*98304
  float* A0p    = Sp    + NCHUNK*PAIR;     // 6*98304
  float* A1p    = A0p   + NCHUNK*PAIR;     // 6*98304
  float* A2p    = A1p   + NCHUNK*PAIR;     // 6*98304
  float* apart  = A2p   + NCHUNK*PAIR;     // 384
  unsigned int* ticket = (unsigned int*)(apart + NPOST);

  hipLaunchKernelGGL(k_pre, dim3(1), dim3(256), 0, stream,
                     x, Wa1, ba1, Wb1, bb1, Wa2, ba2, Wb2, bb2,
                     Wa3, ba3, Wb3, bb3, norms, A3mT, B3mT, apart, ticket);
  hipLaunchKernelGGL(k_main, dim3(NPTS, NCHUNK), dim3(128), 0, stream,
                     x, norms, A3mT, B3mT, Mp, Sp, A0p, A1p, A2p);
  hipLaunchKernelGGL(k_post, dim3(NPOST), dim3(256), 0, stream,
                     x, Mp, Sp, A0p, A1p, A2p, Wf, apart, ticket, out);
}

// Round 6
// 216.174 us; speedup vs baseline: 1.1872x; 1.1872x over previous
//
#include <hip/hip_runtime.h>

#define NPTS 768
#define CCH  128
#define NM4  36    // 35 deg<=4 monomials in (d,u,v) + 1 pad
#define NM2  10    // deg<=2 monomials
#define TILE 128
#define NCHUNK 6   // one 128-tile of n per block
#define PAIR (NPTS*CCH)
#define NACC 384   // apart accumulator size (3 x 128)
#define FINB 96    // k_fin grid
#define LOG2E 1.4426950408889634f

__device__ __forceinline__ float fast_exp2(float x) {
  return __builtin_amdgcn_exp2f(x);   // v_exp_f32 (base-2)
}

// ---- monomial index helpers (compile-time foldable under full unroll) ------
__device__ __forceinline__ int t4i(int a, int b, int c) {
  int t = 0;
  for (int aa = 0; aa < a; ++aa) t += (5 - aa) * (6 - aa) / 2;
  for (int bb = 0; bb < b; ++bb) t += (5 - a - bb);
  return t + c;
}
__device__ __forceinline__ int t2i(int a, int b, int c) {
  int t = 0;
  for (int aa = 0; aa < a; ++aa) t += (3 - aa) * (4 - aa) / 2;
  for (int bb = 0; bb < b; ++bb) t += (3 - a - bb);
  return t + c;
}

// ---------------------------------------------------------------------------
// P1 (1 block, 256 thr): norms; layer-1/2 polynomial fold -> C2m (global).
// Also zeroes k_fin's accumulator + ticket (stream-ordered before k_fin).
// ---------------------------------------------------------------------------
__global__ __launch_bounds__(256) void k_pre1(
    const float* __restrict__ x,
    const float* __restrict__ Wa1, const float* __restrict__ ba1,
    const float* __restrict__ Wb1, const float* __restrict__ bb1,
    const float* __restrict__ Wa2, const float* __restrict__ ba2,
    const float* __restrict__ Wb2, const float* __restrict__ bb2,
    float* __restrict__ norms, float* __restrict__ C2m,
    float* __restrict__ apart, unsigned int* __restrict__ ticket) {
  __shared__ float C1m[CCH][NM2];
  __shared__ float A2m[CCH][NM2];
  __shared__ float B2m[CCH][NM2];
  const int tid = threadIdx.x;

  for (int i = tid; i < NACC; i += 256) apart[i] = 0.f;
  if (tid == 0) *ticket = 0u;

  for (int i = tid; i < NPTS; i += 256) {
    float a = x[3*i], b = x[3*i+1], c = x[3*i+2];
    norms[i] = sqrtf(a*a + b*b + c*c);
  }
  if (tid < CCH) {
    const int c = tid;
    float La[4] = {Wa1[3*c], Wa1[3*c+1], Wa1[3*c+2], ba1[c]};
    float Lb[4] = {Wb1[3*c], Wb1[3*c+1], Wb1[3*c+2], bb1[c]};
    float acc[NM2];
    #pragma unroll
    for (int t = 0; t < NM2; ++t) acc[t] = 0.f;
    #pragma unroll
    for (int p = 0; p < 4; ++p)
      #pragma unroll
      for (int q = 0; q < 4; ++q) {
        const int ea = (p==0) + (q==0);
        const int eb = (p==1) + (q==1);
        const int ec = (p==2) + (q==2);
        acc[t2i(ea, eb, ec)] += La[p]*Lb[q];
      }
    #pragma unroll
    for (int t = 0; t < NM2; ++t) C1m[c][t] = acc[t];
  }
  __syncthreads();
  for (int idx = tid; idx < CCH*NM2; idx += 256) {
    const int c = idx / NM2, t = idx % NM2;
    float sa = 0.f, sb = 0.f;
    for (int k = 0; k < CCH; ++k) {
      const float v = C1m[k][t];
      sa += Wa2[c*CCH + k] * v;
      sb += Wb2[c*CCH + k] * v;
    }
    if (t == 0) { sa += ba2[c]; sb += bb2[c]; }
    A2m[c][t] = sa; B2m[c][t] = sb;
  }
  __syncthreads();
  if (tid < CCH) {
    const int c = tid;
    float acc[35];
    #pragma unroll
    for (int t = 0; t < 35; ++t) acc[t] = 0.f;
    #pragma unroll
    for (int a1 = 0; a1 <= 2; ++a1)
      #pragma unroll
      for (int b1 = 0; b1 <= 2; ++b1)
        #pragma unroll
        for (int c1 = 0; c1 <= 2; ++c1)
          if (a1 + b1 + c1 <= 2) {
            const float av = A2m[c][t2i(a1,b1,c1)];
            #pragma unroll
            for (int a2 = 0; a2 <= 2; ++a2)
              #pragma unroll
              for (int b2 = 0; b2 <= 2; ++b2)
                #pragma unroll
                for (int c2 = 0; c2 <= 2; ++c2)
                  if (a2 + b2 + c2 <= 2)
                    acc[t4i(a1+a2, b1+b2, c1+c2)] += av * B2m[c][t2i(a2,b2,c2)];
          }
    #pragma unroll
    for (int t = 0; t < 35; ++t) C2m[c*NM4 + t] = acc[t];
    C2m[c*NM4 + 35] = 0.f;
  }
}

// ---------------------------------------------------------------------------
// P2 (128 blocks x 64 thr): A3mT/B3mT = layer-3 fold, transposed (36 x 128).
// ---------------------------------------------------------------------------
__global__ void k_pre2(const float* __restrict__ Wa3, const float* __restrict__ ba3,
                       const float* __restrict__ Wb3, const float* __restrict__ bb3,
                       const float* __restrict__ C2m,
                       float* __restrict__ A3mT, float* __restrict__ B3mT) {
  const int c = blockIdx.x;
  const int j = threadIdx.x;
  if (j >= NM4) return;
  float sa = 0.f, sb = 0.f;
  if (j < 35) {
    for (int k = 0; k < CCH; ++k) {
      const float v = C2m[k*NM4 + j];
      sa += Wa3[c*CCH + k] * v;
      sb += Wb3[c*CCH + k] * v;
    }
    if (j == 0) { sa += ba3[c]; sb += bb3[c]; }
  }
  A3mT[j*CCH + c] = sa;
  B3mT[j*CCH + c] = sb;
}

// ---------------------------------------------------------------------------
// k_main: block = (m-pair, n-chunk of 128), 256 threads = 2 m-halves x 128 c.
// 18 KB LDS -> 8 blocks/CU = 32 waves/CU. Online softmax (log2 domain) +
// x-weighted accumulators; scalar fp32 dots (R4-proven codegen).
// ---------------------------------------------------------------------------
__global__ __launch_bounds__(256) void k_main(
    const float* __restrict__ x, const float* __restrict__ norms,
    const float* __restrict__ A3mT, const float* __restrict__ B3mT,
    float* __restrict__ Mp, float* __restrict__ Sp,
    float* __restrict__ A0p, float* __restrict__ A1p, float* __restrict__ A2p) {
  __shared__ __align__(16) float wlds[2][TILE][16];
  __shared__ __align__(16) float xt[TILE][4];
  const int tid = threadIdx.x;
  const int mi = tid >> 7;
  const int c = tid & 127;
  const int m = blockIdx.x*2 + mi;
  const int chunk = blockIdx.y;

  const float u = norms[m];
  const float xm0 = x[3*m], xm1 = x[3*m+1], xm2 = x[3*m+2];

  // Build this half's psi row (n = chunk*128 + c) into LDS.
  {
    const int n = chunk*TILE + c;
    const float v = norms[n];
    const float x0 = x[3*n], x1 = x[3*n+1], x2 = x[3*n+2];
    const float dot = xm0*x0 + xm1*x1 + xm2*x2;
    float d2 = u*u + v*v - 2.f*dot;
    float d  = (d2 > 0.f) ? sqrtf(d2) : 0.f;
    float dp[5], vp[5];
    dp[0] = 1.f; vp[0] = 1.f;
    #pragma unroll
    for (int i = 1; i < 5; ++i) { dp[i] = dp[i-1]*d; vp[i] = vp[i-1]*v; }
    float wv[16]; int t = 0;
    #pragma unroll
    for (int i = 0; i <= 4; ++i)
      #pragma unroll
      for (int j = 0; i + j <= 4; ++j) wv[t++] = dp[i]*vp[j];
    wv[15] = 0.f;
    float4* dst = (float4*)&wlds[mi][c][0];
    dst[0] = make_float4(wv[0],  wv[1],  wv[2],  wv[3]);
    dst[1] = make_float4(wv[4],  wv[5],  wv[6],  wv[7]);
    dst[2] = make_float4(wv[8],  wv[9],  wv[10], wv[11]);
    dst[3] = make_float4(wv[12], wv[13], wv[14], wv[15]);
    if (mi == 0) *(float4*)&xt[c][0] = make_float4(x0, x1, x2, 0.f);
  }

  // Fold u-powers into per-channel coefficients; log2e folded into cA.
  float upow[5]; upow[0] = 1.f;
  #pragma unroll
  for (int b = 1; b < 5; ++b) upow[b] = upow[b-1]*u;
  float cA[16], cB[16];
  {
    int t = 0;
    #pragma unroll
    for (int i = 0; i <= 4; ++i)
      #pragma unroll
      for (int j = 0; i + j <= 4; ++j) {
        float sa = 0.f, sb = 0.f;
        #pragma unroll
        for (int b = 0; i + j + b <= 4; ++b) {
          const int t4 = t4i(i, b, j);   // (deg d, deg u, deg v)
          sa += A3mT[t4*CCH + c]*upow[b];
          sb += B3mT[t4*CCH + c]*upow[b];
        }
        cA[t] = sa*LOG2E; cB[t] = sb; ++t;
      }
    cA[15] = 0.f; cB[15] = 0.f;
  }

  __syncthreads();

  float mrun = -INFINITY, srun = 0.f, a0 = 0.f, a1 = 0.f, a2 = 0.f;
  #pragma unroll 2
  for (int nn = 0; nn < TILE; ++nn) {
    const float4* pv = (const float4*)&wlds[mi][nn][0];
    const float4 p0 = pv[0], p1 = pv[1], p2 = pv[2], p3 = pv[3];
    const float4 xq = *(const float4*)&xt[nn][0];
    float laA = cA[0]*p0.x + cA[1]*p0.y + cA[2]*p0.z + cA[3]*p0.w
              + cA[4]*p1.x + cA[5]*p1.y + cA[6]*p1.z + cA[7]*p1.w;
    float laB = cA[8]*p2.x + cA[9]*p2.y + cA[10]*p2.z + cA[11]*p2.w
              + cA[12]*p3.x + cA[13]*p3.y + cA[14]*p3.z;
    float lbA = cB[0]*p0.x + cB[1]*p0.y + cB[2]*p0.z + cB[3]*p0.w
              + cB[4]*p1.x + cB[5]*p1.y + cB[6]*p1.z + cB[7]*p1.w;
    float lbB = cB[8]*p2.x + cB[9]*p2.y + cB[10]*p2.z + cB[11]*p2.w
              + cB[12]*p3.x + cB[13]*p3.y + cB[14]*p3.z;
    const float h2 = (laA + laB) * (lbA + lbB);   // h * log2e
    const float mnew = fmaxf(mrun, h2);
    const float scale = fast_exp2(mrun - mnew);
    const float e = fast_exp2(h2 - mnew);
    srun = fmaf(srun, scale, e);
    a0 = fmaf(a0, scale, e*xq.x);
    a1 = fmaf(a1, scale, e*xq.y);
    a2 = fmaf(a2, scale, e*xq.z);
    mrun = mnew;
  }
  const int idx = chunk*PAIR + m*CCH + c;
  Mp[idx] = mrun; Sp[idx] = srun;
  A0p[idx] = a0; A1p[idx] = a1; A2p[idx] = a2;
}

// ---------------------------------------------------------------------------
// k_fin (96 blocks x 256): per block 8 m-rows -> merge 6 chunk-partials per
// (m,c), normalize, accumulate; LDS-reduce; 384 atomics/block into apart;
// last block (ticket) does the Wf contraction and writes out.
// ---------------------------------------------------------------------------
__global__ __launch_bounds__(256) void k_fin(
    const float* __restrict__ x,
    const float* __restrict__ Mp, const float* __restrict__ Sp,
    const float* __restrict__ A0p, const float* __restrict__ A1p,
    const float* __restrict__ A2p,
    const float* __restrict__ Wf,
    float* __restrict__ apart, unsigned int* __restrict__ ticket,
    float* __restrict__ out) {
  __shared__ float red2[2][3][CCH];
  __shared__ float red[CCH][6];
  __shared__ bool last;
  const int tid = threadIdx.x;
  const int ml = tid >> 7;
  const int c = tid & 127;

  float s0 = 0.f, s1 = 0.f, s2 = 0.f;
  #pragma unroll
  for (int j = 0; j < 4; ++j) {
    const int m = blockIdx.x*8 + ml*4 + j;
    const int gid = m*CCH + c;
    float mv[NCHUNK];
    float M = -INFINITY;
    #pragma unroll
    for (int ch = 0; ch < NCHUNK; ++ch) {
      mv[ch] = Mp[ch*PAIR + gid];
      M = fmaxf(M, mv[ch]);
    }
    float W = 0.f, g0 = 0.f, g1 = 0.f, g2 = 0.f;
    #pragma unroll
    for (int ch = 0; ch < NCHUNK; ++ch) {
      const float s = fast_exp2(mv[ch] - M);
      W  = fmaf(Sp [ch*PAIR + gid], s, W);
      g0 = fmaf(A0p[ch*PAIR + gid], s, g0);
      g1 = fmaf(A1p[ch*PAIR + gid], s, g1);
      g2 = fmaf(A2p[ch*PAIR + gid], s, g2);
    }
    const float inv = 1.f / W;
    s0 = fmaf(g0, inv, s0);
    s1 = fmaf(g1, inv, s1);
    s2 = fmaf(g2, inv, s2);
  }
  red2[ml][0][c] = s0; red2[ml][1][c] = s1; red2[ml][2][c] = s2;
  __syncthreads();
  for (int p = tid; p < NACC; p += 256) {
    const int i = p >> 7, cc = p & 127;
    atomicAdd(&apart[p], red2[0][i][cc] + red2[1][i][cc]);
  }
  __threadfence();
  __syncthreads();
  if (tid == 0) {
    const unsigned int old = atomicAdd(ticket, 1u);
    last = (old == FINB - 1);
  }
  __syncthreads();
  if (!last) return;
  __threadfence();

  if (tid < CCH) {
    const int cc = tid;
    const float a0 = __hip_atomic_load(&apart[cc],          __ATOMIC_RELAXED, __HIP_MEMORY_SCOPE_AGENT);
    const float a1 = __hip_atomic_load(&apart[CCH + cc],    __ATOMIC_RELAXED, __HIP_MEMORY_SCOPE_AGENT);
    const float a2 = __hip_atomic_load(&apart[2*CCH + cc],  __ATOMIC_RELAXED, __HIP_MEMORY_SCOPE_AGENT);
    const float w0 = Wf[cc], w1 = Wf[CCH + cc];
    red[cc][0] = w0*a0; red[cc][1] = w0*a1; red[cc][2] = w0*a2;
    red[cc][3] = w1*a0; red[cc][4] = w1*a1; red[cc][5] = w1*a2;
  }
  __syncthreads();
  if (tid < 6) {
    float s = 0.f;
    for (int k = 0; k < CCH; ++k) s += red[k][tid];
    out[3 + tid] = s;
  }
  if (tid < 3) out[tid] = x[tid];
}

// ---------------------------------------------------------------------------
extern "C" void kernel_launch(void* const* d_in, const int* in_sizes, int n_in,
                              void* d_out, int out_size, void* d_ws, size_t ws_size,
                              hipStream_t stream) {
  const float* x   = (const float*)d_in[0];
  const float* Wa1 = (const float*)d_in[1];
  const float* ba1 = (const float*)d_in[2];
  const float* Wb1 = (const float*)d_in[3];
  const float* bb1 = (const float*)d_in[4];
  const float* Wa2 = (const float*)d_in[5];
  const float* ba2 = (const float*)d_in[6];
  const float* Wb2 = (const float*)d_in[7];
  const float* bb2 = (const float*)d_in[8];
  const float* Wa3 = (const float*)d_in[9];
  const float* ba3 = (const float*)d_in[10];
  const float* Wb3 = (const float*)d_in[11];
  const float* bb3 = (const float*)d_in[12];
  const float* Wf  = (const float*)d_in[13];
  float* out = (float*)d_out;

  float* ws     = (float*)d_ws;
  float* norms  = ws;                      // 768
  float* C2m    = norms + NPTS;            // 128*36
  float* A3mT   = C2m   + CCH*NM4;         // 36*128
  float* B3mT   = A3mT  + NM4*CCH;         // 36*128
  float* Mp     = B3mT  + NM4*CCH;         // 6*98304
  float* Sp     = Mp    + NCHUNK*PAIR;     // 6*98304
  float* A0p    = Sp    + NCHUNK*PAIR;     // 6*98304
  float* A1p    = A0p   + NCHUNK*PAIR;     // 6*98304
  float* A2p    = A1p   + NCHUNK*PAIR;     // 6*98304
  float* apart  = A2p   + NCHUNK*PAIR;     // 384
  unsigned int* ticket = (unsigned int*)(apart + NACC);

  hipLaunchKernelGGL(k_pre1, dim3(1), dim3(256), 0, stream,
                     x, Wa1, ba1, Wb1, bb1, Wa2, ba2, Wb2, bb2,
                     norms, C2m, apart, ticket);
  hipLaunchKernelGGL(k_pre2, dim3(CCH), dim3(64), 0, stream,
                     Wa3, ba3, Wb3, bb3, C2m, A3mT, B3mT);
  hipLaunchKernelGGL(k_main, dim3(NPTS/2, NCHUNK), dim3(256), 0, stream,
                     x, norms, A3mT, B3mT, Mp, Sp, A0p, A1p, A2p);
  hipLaunchKernelGGL(k_fin, dim3(FINB), dim3(256), 0, stream,
                     x, Mp, Sp, A0p, A1p, A2p, Wf, apart, ticket, out);
}

// Round 7
// 201.989 us; speedup vs baseline: 1.2705x; 1.0702x over previous
//
#include <hip/hip_runtime.h>

#define NPTS 768
#define CCH  128
#define NM4  36    // 35 deg<=4 monomials in (d,u,v) + 1 pad
#define NM2  10    // deg<=2 monomials
#define TILE 128
#define NCHUNK 6   // one 128-tile of n per block
#define PAIR (NPTS*CCH)
#define NACC 384   // apart accumulator size (3 x 128)
#define FINB 96    // k_fin grid
#define LOG2E 1.4426950408889634f

__device__ __forceinline__ float fast_exp2(float x) {
  return __builtin_amdgcn_exp2f(x);   // v_exp_f32 (base-2)
}

// ---- monomial index helpers (compile-time foldable under full unroll) ------
__device__ __forceinline__ int t4i(int a, int b, int c) {
  int t = 0;
  for (int aa = 0; aa < a; ++aa) t += (5 - aa) * (6 - aa) / 2;
  for (int bb = 0; bb < b; ++bb) t += (5 - a - bb);
  return t + c;
}
__device__ __forceinline__ int t2i(int a, int b, int c) {
  int t = 0;
  for (int aa = 0; aa < a; ++aa) t += (3 - aa) * (4 - aa) / 2;
  for (int bb = 0; bb < b; ++bb) t += (3 - a - bb);
  return t + c;
}

// ---------------------------------------------------------------------------
// k_preA (7 blocks x 128): blocks 0-5 compute norms; block 6 zeroes the
// k_fin accumulator/ticket and computes C1m (layer-1 quadratic coeffs).
// ---------------------------------------------------------------------------
__global__ __launch_bounds__(128) void k_preA(
    const float* __restrict__ x,
    const float* __restrict__ Wa1, const float* __restrict__ ba1,
    const float* __restrict__ Wb1, const float* __restrict__ bb1,
    float* __restrict__ norms, float* __restrict__ C1m,
    float* __restrict__ apart, unsigned int* __restrict__ ticket) {
  const int tid = threadIdx.x;
  const int bid = blockIdx.x;
  if (bid < 6) {
    const int i = bid*128 + tid;
    const float a = x[3*i], b = x[3*i+1], c = x[3*i+2];
    norms[i] = sqrtf(a*a + b*b + c*c);
    return;
  }
  #pragma unroll
  for (int r = 0; r < 3; ++r) apart[r*128 + tid] = 0.f;
  if (tid == 0) *ticket = 0u;

  const int c = tid;
  const float La[4] = {Wa1[3*c], Wa1[3*c+1], Wa1[3*c+2], ba1[c]};
  const float Lb[4] = {Wb1[3*c], Wb1[3*c+1], Wb1[3*c+2], bb1[c]};
  float acc[NM2];
  #pragma unroll
  for (int t = 0; t < NM2; ++t) acc[t] = 0.f;
  #pragma unroll
  for (int p = 0; p < 4; ++p)
    #pragma unroll
    for (int q = 0; q < 4; ++q) {
      const int ea = (p==0) + (q==0);
      const int eb = (p==1) + (q==1);
      const int ec = (p==2) + (q==2);
      acc[t2i(ea, eb, ec)] += La[p]*Lb[q];
    }
  #pragma unroll
  for (int t = 0; t < NM2; ++t) C1m[c*NM2 + t] = acc[t];
}

// ---------------------------------------------------------------------------
// k_fold2 (128 blocks = channel c, 128 threads = k): layer-2 fold with
// coalesced W2 row loads + LDS tree reduction; thread 0 then expands the
// (A2.B2) product to deg-4 monomial coeffs C2m[c][35].
// ---------------------------------------------------------------------------
__global__ __launch_bounds__(128) void k_fold2(
    const float* __restrict__ Wa2, const float* __restrict__ ba2,
    const float* __restrict__ Wb2, const float* __restrict__ bb2,
    const float* __restrict__ C1m, float* __restrict__ C2m) {
  __shared__ float sA[128][NM2];
  __shared__ float sB[128][NM2];
  const int c = blockIdx.x;
  const int k = threadIdx.x;

  const float wa = Wa2[c*CCH + k];
  const float wb = Wb2[c*CCH + k];
  #pragma unroll
  for (int t = 0; t < NM2; ++t) {
    const float v = C1m[k*NM2 + t];
    sA[k][t] = wa * v;
    sB[k][t] = wb * v;
  }
  __syncthreads();
  #pragma unroll
  for (int s = 64; s >= 1; s >>= 1) {
    if (k < s) {
      #pragma unroll
      for (int t = 0; t < NM2; ++t) {
        sA[k][t] += sA[k+s][t];
        sB[k][t] += sB[k+s][t];
      }
    }
    __syncthreads();
  }
  if (k == 0) {
    float A2[NM2], B2[NM2];
    #pragma unroll
    for (int t = 0; t < NM2; ++t) { A2[t] = sA[0][t]; B2[t] = sB[0][t]; }
    A2[0] += ba2[c]; B2[0] += bb2[c];    // constant monomial
    float acc[35];
    #pragma unroll
    for (int t = 0; t < 35; ++t) acc[t] = 0.f;
    #pragma unroll
    for (int a1 = 0; a1 <= 2; ++a1)
      #pragma unroll
      for (int b1 = 0; b1 <= 2; ++b1)
        #pragma unroll
        for (int c1 = 0; c1 <= 2; ++c1)
          if (a1 + b1 + c1 <= 2) {
            const float av = A2[t2i(a1,b1,c1)];
            #pragma unroll
            for (int a2 = 0; a2 <= 2; ++a2)
              #pragma unroll
              for (int b2 = 0; b2 <= 2; ++b2)
                #pragma unroll
                for (int c2 = 0; c2 <= 2; ++c2)
                  if (a2 + b2 + c2 <= 2)
                    acc[t4i(a1+a2, b1+b2, c1+c2)] += av * B2[t2i(a2,b2,c2)];
          }
    #pragma unroll
    for (int t = 0; t < 35; ++t) C2m[c*NM4 + t] = acc[t];
    C2m[c*NM4 + 35] = 0.f;
  }
}

// ---------------------------------------------------------------------------
// k_pre2 (128 blocks x 64 thr): A3mT/B3mT = layer-3 fold, transposed (36x128).
// ---------------------------------------------------------------------------
__global__ void k_pre2(const float* __restrict__ Wa3, const float* __restrict__ ba3,
                       const float* __restrict__ Wb3, const float* __restrict__ bb3,
                       const float* __restrict__ C2m,
                       float* __restrict__ A3mT, float* __restrict__ B3mT) {
  const int c = blockIdx.x;
  const int j = threadIdx.x;
  if (j >= NM4) return;
  float sa = 0.f, sb = 0.f;
  if (j < 35) {
    for (int k = 0; k < CCH; ++k) {
      const float v = C2m[k*NM4 + j];
      sa += Wa3[c*CCH + k] * v;
      sb += Wb3[c*CCH + k] * v;
    }
    if (j == 0) { sa += ba3[c]; sb += bb3[c]; }
  }
  A3mT[j*CCH + c] = sa;
  B3mT[j*CCH + c] = sb;
}

// ---------------------------------------------------------------------------
// k_main: block = (m-pair, n-chunk of 128), 256 threads = 2 m-halves x 128 c.
// 18 KB LDS -> 8 blocks/CU. Online softmax (log2 domain) + x-weighted accum.
// ---------------------------------------------------------------------------
__global__ __launch_bounds__(256) void k_main(
    const float* __restrict__ x, const float* __restrict__ norms,
    const float* __restrict__ A3mT, const float* __restrict__ B3mT,
    float* __restrict__ Mp, float* __restrict__ Sp,
    float* __restrict__ A0p, float* __restrict__ A1p, float* __restrict__ A2p) {
  __shared__ __align__(16) float wlds[2][TILE][16];
  __shared__ __align__(16) float xt[TILE][4];
  const int tid = threadIdx.x;
  const int mi = tid >> 7;
  const int c = tid & 127;
  const int m = blockIdx.x*2 + mi;
  const int chunk = blockIdx.y;

  const float u = norms[m];
  const float xm0 = x[3*m], xm1 = x[3*m+1], xm2 = x[3*m+2];

  // Build this half's psi row (n = chunk*128 + c) into LDS.
  {
    const int n = chunk*TILE + c;
    const float v = norms[n];
    const float x0 = x[3*n], x1 = x[3*n+1], x2 = x[3*n+2];
    const float dot = xm0*x0 + xm1*x1 + xm2*x2;
    float d2 = u*u + v*v - 2.f*dot;
    float d  = (d2 > 0.f) ? sqrtf(d2) : 0.f;
    float dp[5], vp[5];
    dp[0] = 1.f; vp[0] = 1.f;
    #pragma unroll
    for (int i = 1; i < 5; ++i) { dp[i] = dp[i-1]*d; vp[i] = vp[i-1]*v; }
    float wv[16]; int t = 0;
    #pragma unroll
    for (int i = 0; i <= 4; ++i)
      #pragma unroll
      for (int j = 0; i + j <= 4; ++j) wv[t++] = dp[i]*vp[j];
    wv[15] = 0.f;
    float4* dst = (float4*)&wlds[mi][c][0];
    dst[0] = make_float4(wv[0],  wv[1],  wv[2],  wv[3]);
    dst[1] = make_float4(wv[4],  wv[5],  wv[6],  wv[7]);
    dst[2] = make_float4(wv[8],  wv[9],  wv[10], wv[11]);
    dst[3] = make_float4(wv[12], wv[13], wv[14], wv[15]);
    if (mi == 0) *(float4*)&xt[c][0] = make_float4(x0, x1, x2, 0.f);
  }

  // Fold u-powers into per-channel coefficients; log2e folded into cA.
  float upow[5]; upow[0] = 1.f;
  #pragma unroll
  for (int b = 1; b < 5; ++b) upow[b] = upow[b-1]*u;
  float cA[16], cB[16];
  {
    int t = 0;
    #pragma unroll
    for (int i = 0; i <= 4; ++i)
      #pragma unroll
      for (int j = 0; i + j <= 4; ++j) {
        float sa = 0.f, sb = 0.f;
        #pragma unroll
        for (int b = 0; i + j + b <= 4; ++b) {
          const int t4 = t4i(i, b, j);   // (deg d, deg u, deg v)
          sa += A3mT[t4*CCH + c]*upow[b];
          sb += B3mT[t4*CCH + c]*upow[b];
        }
        cA[t] = sa*LOG2E; cB[t] = sb; ++t;
      }
    cA[15] = 0.f; cB[15] = 0.f;
  }

  __syncthreads();

  float mrun = -INFINITY, srun = 0.f, a0 = 0.f, a1 = 0.f, a2 = 0.f;
  #pragma unroll 2
  for (int nn = 0; nn < TILE; ++nn) {
    const float4* pv = (const float4*)&wlds[mi][nn][0];
    const float4 p0 = pv[0], p1 = pv[1], p2 = pv[2], p3 = pv[3];
    const float4 xq = *(const float4*)&xt[nn][0];
    float laA = cA[0]*p0.x + cA[1]*p0.y + cA[2]*p0.z + cA[3]*p0.w
              + cA[4]*p1.x + cA[5]*p1.y + cA[6]*p1.z + cA[7]*p1.w;
    float laB = cA[8]*p2.x + cA[9]*p2.y + cA[10]*p2.z + cA[11]*p2.w
              + cA[12]*p3.x + cA[13]*p3.y + cA[14]*p3.z;
    float lbA = cB[0]*p0.x + cB[1]*p0.y + cB[2]*p0.z + cB[3]*p0.w
              + cB[4]*p1.x + cB[5]*p1.y + cB[6]*p1.z + cB[7]*p1.w;
    float lbB = cB[8]*p2.x + cB[9]*p2.y + cB[10]*p2.z + cB[11]*p2.w
              + cB[12]*p3.x + cB[13]*p3.y + cB[14]*p3.z;
    const float h2 = (laA + laB) * (lbA + lbB);   // h * log2e
    const float mnew = fmaxf(mrun, h2);
    const float scale = fast_exp2(mrun - mnew);
    const float e = fast_exp2(h2 - mnew);
    srun = fmaf(srun, scale, e);
    a0 = fmaf(a0, scale, e*xq.x);
    a1 = fmaf(a1, scale, e*xq.y);
    a2 = fmaf(a2, scale, e*xq.z);
    mrun = mnew;
  }
  const int idx = chunk*PAIR + m*CCH + c;
  Mp[idx] = mrun; Sp[idx] = srun;
  A0p[idx] = a0; A1p[idx] = a1; A2p[idx] = a2;
}

// ---------------------------------------------------------------------------
// k_fin (96 blocks x 256): merge chunk partials per (m,c), normalize,
// LDS-reduce 8 m-rows, 384 atomics/block into apart; last block (ticket)
// does the Wf contraction and writes out.
// ---------------------------------------------------------------------------
__global__ __launch_bounds__(256) void k_fin(
    const float* __restrict__ x,
    const float* __restrict__ Mp, const float* __restrict__ Sp,
    const float* __restrict__ A0p, const float* __restrict__ A1p,
    const float* __restrict__ A2p,
    const float* __restrict__ Wf,
    float* __restrict__ apart, unsigned int* __restrict__ ticket,
    float* __restrict__ out) {
  __shared__ float red2[2][3][CCH];
  __shared__ float red[CCH][6];
  __shared__ bool last;
  const int tid = threadIdx.x;
  const int ml = tid >> 7;
  const int c = tid & 127;

  float s0 = 0.f, s1 = 0.f, s2 = 0.f;
  #pragma unroll
  for (int j = 0; j < 4; ++j) {
    const int m = blockIdx.x*8 + ml*4 + j;
    const int gid = m*CCH + c;
    float mv[NCHUNK];
    float M = -INFINITY;
    #pragma unroll
    for (int ch = 0; ch < NCHUNK; ++ch) {
      mv[ch] = Mp[ch*PAIR + gid];
      M = fmaxf(M, mv[ch]);
    }
    float W = 0.f, g0 = 0.f, g1 = 0.f, g2 = 0.f;
    #pragma unroll
    for (int ch = 0; ch < NCHUNK; ++ch) {
      const float s = fast_exp2(mv[ch] - M);
      W  = fmaf(Sp [ch*PAIR + gid], s, W);
      g0 = fmaf(A0p[ch*PAIR + gid], s, g0);
      g1 = fmaf(A1p[ch*PAIR + gid], s, g1);
      g2 = fmaf(A2p[ch*PAIR + gid], s, g2);
    }
    const float inv = 1.f / W;
    s0 = fmaf(g0, inv, s0);
    s1 = fmaf(g1, inv, s1);
    s2 = fmaf(g2, inv, s2);
  }
  red2[ml][0][c] = s0; red2[ml][1][c] = s1; red2[ml][2][c] = s2;
  __syncthreads();
  for (int p = tid; p < NACC; p += 256) {
    const int i = p >> 7, cc = p & 127;
    atomicAdd(&apart[p], red2[0][i][cc] + red2[1][i][cc]);
  }
  __threadfence();
  __syncthreads();
  if (tid == 0) {
    const unsigned int old = atomicAdd(ticket, 1u);
    last = (old == FINB - 1);
  }
  __syncthreads();
  if (!last) return;
  __threadfence();

  if (tid < CCH) {
    const int cc = tid;
    const float a0 = __hip_atomic_load(&apart[cc],          __ATOMIC_RELAXED, __HIP_MEMORY_SCOPE_AGENT);
    const float a1 = __hip_atomic_load(&apart[CCH + cc],    __ATOMIC_RELAXED, __HIP_MEMORY_SCOPE_AGENT);
    const float a2 = __hip_atomic_load(&apart[2*CCH + cc],  __ATOMIC_RELAXED, __HIP_MEMORY_SCOPE_AGENT);
    const float w0 = Wf[cc], w1 = Wf[CCH + cc];
    red[cc][0] = w0*a0; red[cc][1] = w0*a1; red[cc][2] = w0*a2;
    red[cc][3] = w1*a0; red[cc][4] = w1*a1; red[cc][5] = w1*a2;
  }
  __syncthreads();
  if (tid < 6) {
    float s = 0.f;
    for (int k = 0; k < CCH; ++k) s += red[k][tid];
    out[3 + tid] = s;
  }
  if (tid < 3) out[tid] = x[tid];
}

// ---------------------------------------------------------------------------
extern "C" void kernel_launch(void* const* d_in, const int* in_sizes, int n_in,
                              void* d_out, int out_size, void* d_ws, size_t ws_size,
                              hipStream_t stream) {
  const float* x   = (const float*)d_in[0];
  const float* Wa1 = (const float*)d_in[1];
  const float* ba1 = (const float*)d_in[2];
  const float* Wb1 = (const float*)d_in[3];
  const float* bb1 = (const float*)d_in[4];
  const float* Wa2 = (const float*)d_in[5];
  const float* ba2 = (const float*)d_in[6];
  const float* Wb2 = (const float*)d_in[7];
  const float* bb2 = (const float*)d_in[8];
  const float* Wa3 = (const float*)d_in[9];
  const float* ba3 = (const float*)d_in[10];
  const float* Wb3 = (const float*)d_in[11];
  const float* bb3 = (const float*)d_in[12];
  const float* Wf  = (const float*)d_in[13];
  float* out = (float*)d_out;

  float* ws     = (float*)d_ws;
  float* norms  = ws;                      // 768
  float* C1m    = norms + NPTS;            // 128*10
  float* C2m    = C1m   + CCH*NM2;         // 128*36
  float* A3mT   = C2m   + CCH*NM4;         // 36*128
  float* B3mT   = A3mT  + NM4*CCH;         // 36*128
  float* Mp     = B3mT  + NM4*CCH;         // 6*98304
  float* Sp     = Mp    + NCHUNK*PAIR;     // 6*98304
  float* A0p    = Sp    + NCHUNK*PAIR;     // 6*98304
  float* A1p    = A0p   + NCHUNK*PAIR;     // 6*98304
  float* A2p    = A1p   + NCHUNK*PAIR;     // 6*98304
  float* apart  = A2p   + NCHUNK*PAIR;     // 384
  unsigned int* ticket = (unsigned int*)(apart + NACC);

  hipLaunchKernelGGL(k_preA, dim3(7), dim3(128), 0, stream,
                     x, Wa1, ba1, Wb1, bb1, norms, C1m, apart, ticket);
  hipLaunchKernelGGL(k_fold2, dim3(CCH), dim3(128), 0, stream,
                     Wa2, ba2, Wb2, bb2, C1m, C2m);
  hipLaunchKernelGGL(k_pre2, dim3(CCH), dim3(64), 0, stream,
                     Wa3, ba3, Wb3, bb3, C2m, A3mT, B3mT);
  hipLaunchKernelGGL(k_main, dim3(NPTS/2, NCHUNK), dim3(256), 0, stream,
                     x, norms, A3mT, B3mT, Mp, Sp, A0p, A1p, A2p);
  hipLaunchKernelGGL(k_fin, dim3(FINB), dim3(256), 0, stream,
                     x, Mp, Sp, A0p, A1p, A2p, Wf, apart, ticket, out);
}

// Round 8
// 195.478 us; speedup vs baseline: 1.3129x; 1.0333x over previous
//
#include <hip/hip_runtime.h>

#define NPTS 768
#define CCH  128
#define NM4  36    // 35 deg<=4 monomials in (d,u,v) + 1 pad
#define NM2  10    // deg<=2 monomials
#define TILE 128
#define NCHUNK 6   // one 128-tile of n per block
#define PAIR (NPTS*CCH)
#define NACC 384   // apart accumulator size (3 x 128)
#define FINB 96    // k_fin grid
#define LOG2E 1.4426950408889634f

__device__ __forceinline__ float fast_exp2(float x) {
  return __builtin_amdgcn_exp2f(x);   // v_exp_f32 (base-2)
}

// ---- monomial index helpers ------------------------------------------------
// (a,b,c) = (deg d, deg u, deg v), a outermost. Used at compile time in k_main
// (shallow nest, folds) and at RUNTIME for LDS/global indices (safe: these
// never subscript thread-local arrays).
__device__ __forceinline__ int t4i(int a, int b, int c) {
  int t = 0;
  for (int aa = 0; aa < a; ++aa) t += (5 - aa) * (6 - aa) / 2;
  for (int bb = 0; bb < b; ++bb) t += (5 - a - bb);
  return t + c;
}
__device__ __forceinline__ int t2i(int a, int b, int c) {
  int t = 0;
  for (int aa = 0; aa < a; ++aa) t += (3 - aa) * (4 - aa) / 2;
  for (int bb = 0; bb < b; ++bb) t += (3 - a - bb);
  return t + c;
}

// ---------------------------------------------------------------------------
// k_fold12 (128 blocks = channel c, 128 threads = k):
//   1. thread k: layer-1 quadratic coeffs for channel k as NAMED SCALARS
//      (t2i order: 0:1 1:v 2:v2 3:u 4:uv 5:u2 6:d 7:dv 8:du 9:d2),
//      scaled by Wa2[c,k]/Wb2[c,k], stored to LDS.
//   2. LDS tree-reduce over k -> A2/B2 (deg<=2 coeffs of layer-2 pre-gate).
//   3. threads t<35: gather-compute deg-4 coeff t of A2*B2 -> C2m[c][t].
//   Blocks 0-5 also compute norms; block 6 zeroes apart/ticket.
//   NO dynamically-indexed thread-local arrays anywhere (scratch-spill
//   hazard measured in R6/R7: VGPR=24, ~100 us serial scratch chain).
// ---------------------------------------------------------------------------
__global__ __launch_bounds__(128) void k_fold12(
    const float* __restrict__ x,
    const float* __restrict__ Wa1, const float* __restrict__ ba1,
    const float* __restrict__ Wb1, const float* __restrict__ bb1,
    const float* __restrict__ Wa2, const float* __restrict__ ba2,
    const float* __restrict__ Wb2, const float* __restrict__ bb2,
    float* __restrict__ norms, float* __restrict__ C2m,
    float* __restrict__ apart, unsigned int* __restrict__ ticket) {
  __shared__ float sA[128][NM2];
  __shared__ float sB[128][NM2];
  const int c = blockIdx.x;
  const int k = threadIdx.x;

  if (c < 6) {
    const int i = c*128 + k;
    const float p0 = x[3*i], p1 = x[3*i+1], p2 = x[3*i+2];
    norms[i] = sqrtf(p0*p0 + p1*p1 + p2*p2);
  }
  if (c == 6) {
    apart[k] = 0.f; apart[CCH + k] = 0.f; apart[2*CCH + k] = 0.f;
    if (k == 0) *ticket = 0u;
  }

  // 1. layer-1 coefficients, named scalars, literal LDS column indices
  {
    const float A0 = Wa1[3*k], A1 = Wa1[3*k+1], A2c = Wa1[3*k+2], A3 = ba1[k];
    const float B0 = Wb1[3*k], B1 = Wb1[3*k+1], B2c = Wb1[3*k+2], B3 = bb1[k];
    const float g0 = A3*B3;              // 1
    const float g1 = A2c*B3 + A3*B2c;    // v
    const float g2 = A2c*B2c;            // v^2
    const float g3 = A1*B3 + A3*B1;      // u
    const float g4 = A1*B2c + A2c*B1;    // u v
    const float g5 = A1*B1;              // u^2
    const float g6 = A0*B3 + A3*B0;      // d
    const float g7 = A0*B2c + A2c*B0;    // d v
    const float g8 = A0*B1 + A1*B0;      // d u
    const float g9 = A0*B0;              // d^2
    const float wa = Wa2[c*CCH + k];
    const float wb = Wb2[c*CCH + k];
    sA[k][0] = wa*g0; sB[k][0] = wb*g0;
    sA[k][1] = wa*g1; sB[k][1] = wb*g1;
    sA[k][2] = wa*g2; sB[k][2] = wb*g2;
    sA[k][3] = wa*g3; sB[k][3] = wb*g3;
    sA[k][4] = wa*g4; sB[k][4] = wb*g4;
    sA[k][5] = wa*g5; sB[k][5] = wb*g5;
    sA[k][6] = wa*g6; sB[k][6] = wb*g6;
    sA[k][7] = wa*g7; sB[k][7] = wb*g7;
    sA[k][8] = wa*g8; sB[k][8] = wb*g8;
    sA[k][9] = wa*g9; sB[k][9] = wb*g9;
  }
  __syncthreads();

  // 2. tree reduction over k (LDS-resident accumulators only)
  for (int s = 64; s >= 1; s >>= 1) {
    if (k < s) {
      for (int t = 0; t < NM2; ++t) {
        sA[k][t] += sA[k+s][t];
        sB[k][t] += sB[k+s][t];
      }
    }
    __syncthreads();
  }
  if (k == 0) {          // biases on the constant monomial
    sA[0][0] += ba2[c];
    sB[0][0] += bb2[c];
  }
  __syncthreads();

  // 3. gather-form deg-4 expansion: thread t computes coefficient t
  if (k < 35) {
    // decode t -> (a,b,cc) in t4i order
    int rem = k, a = 0;
    while (rem >= (5 - a)*(6 - a)/2) { rem -= (5 - a)*(6 - a)/2; ++a; }
    int b = 0;
    while (rem >= 5 - a - b) { rem -= 5 - a - b; ++b; }
    const int cc = rem;
    float s = 0.f;
    const int deg = a + b + cc;
    for (int a1 = 0; a1 <= a && a1 <= 2; ++a1)
      for (int b1 = 0; b1 <= b && b1 <= 2; ++b1)
        for (int c1 = 0; c1 <= cc && c1 <= 2; ++c1) {
          const int d1 = a1 + b1 + c1;
          if (d1 <= 2 && (deg - d1) <= 2)
            s += sA[0][t2i(a1, b1, c1)]
               * sB[0][t2i(a - a1, b - b1, cc - c1)];
        }
    C2m[c*NM4 + k] = s;
  }
  if (k == 35) C2m[c*NM4 + 35] = 0.f;
}

// ---------------------------------------------------------------------------
// k_pre2 (128 blocks x 64 thr): A3mT/B3mT = layer-3 fold, transposed (36x128).
// ---------------------------------------------------------------------------
__global__ void k_pre2(const float* __restrict__ Wa3, const float* __restrict__ ba3,
                       const float* __restrict__ Wb3, const float* __restrict__ bb3,
                       const float* __restrict__ C2m,
                       float* __restrict__ A3mT, float* __restrict__ B3mT) {
  const int c = blockIdx.x;
  const int j = threadIdx.x;
  if (j >= NM4) return;
  float sa = 0.f, sb = 0.f;
  if (j < 35) {
    for (int k = 0; k < CCH; ++k) {
      const float v = C2m[k*NM4 + j];
      sa += Wa3[c*CCH + k] * v;
      sb += Wb3[c*CCH + k] * v;
    }
    if (j == 0) { sa += ba3[c]; sb += bb3[c]; }
  }
  A3mT[j*CCH + c] = sa;
  B3mT[j*CCH + c] = sb;
}

// ---------------------------------------------------------------------------
// k_main: block = (m-pair, n-chunk of 128), 256 threads = 2 m-halves x 128 c.
// 18 KB LDS -> 8 blocks/CU. Online softmax (log2 domain) + x-weighted accum.
// ---------------------------------------------------------------------------
__global__ __launch_bounds__(256) void k_main(
    const float* __restrict__ x, const float* __restrict__ norms,
    const float* __restrict__ A3mT, const float* __restrict__ B3mT,
    float* __restrict__ Mp, float* __restrict__ Sp,
    float* __restrict__ A0p, float* __restrict__ A1p, float* __restrict__ A2p) {
  __shared__ __align__(16) float wlds[2][TILE][16];
  __shared__ __align__(16) float xt[TILE][4];
  const int tid = threadIdx.x;
  const int mi = tid >> 7;
  const int c = tid & 127;
  const int m = blockIdx.x*2 + mi;
  const int chunk = blockIdx.y;

  const float u = norms[m];
  const float xm0 = x[3*m], xm1 = x[3*m+1], xm2 = x[3*m+2];

  // Build this half's psi row (n = chunk*128 + c) into LDS.
  {
    const int n = chunk*TILE + c;
    const float v = norms[n];
    const float x0 = x[3*n], x1 = x[3*n+1], x2 = x[3*n+2];
    const float dot = xm0*x0 + xm1*x1 + xm2*x2;
    float d2 = u*u + v*v - 2.f*dot;
    float d  = (d2 > 0.f) ? sqrtf(d2) : 0.f;
    float dp[5], vp[5];
    dp[0] = 1.f; vp[0] = 1.f;
    #pragma unroll
    for (int i = 1; i < 5; ++i) { dp[i] = dp[i-1]*d; vp[i] = vp[i-1]*v; }
    float wv[16]; int t = 0;
    #pragma unroll
    for (int i = 0; i <= 4; ++i)
      #pragma unroll
      for (int j = 0; i + j <= 4; ++j) wv[t++] = dp[i]*vp[j];
    wv[15] = 0.f;
    float4* dst = (float4*)&wlds[mi][c][0];
    dst[0] = make_float4(wv[0],  wv[1],  wv[2],  wv[3]);
    dst[1] = make_float4(wv[4],  wv[5],  wv[6],  wv[7]);
    dst[2] = make_float4(wv[8],  wv[9],  wv[10], wv[11]);
    dst[3] = make_float4(wv[12], wv[13], wv[14], wv[15]);
    if (mi == 0) *(float4*)&xt[c][0] = make_float4(x0, x1, x2, 0.f);
  }

  // Fold u-powers into per-channel coefficients; log2e folded into cA.
  float upow[5]; upow[0] = 1.f;
  #pragma unroll
  for (int b = 1; b < 5; ++b) upow[b] = upow[b-1]*u;
  float cA[16], cB[16];
  {
    int t = 0;
    #pragma unroll
    for (int i = 0; i <= 4; ++i)
      #pragma unroll
      for (int j = 0; i + j <= 4; ++j) {
        float sa = 0.f, sb = 0.f;
        #pragma unroll
        for (int b = 0; i + j + b <= 4; ++b) {
          const int t4 = t4i(i, b, j);   // (deg d, deg u, deg v)
          sa += A3mT[t4*CCH + c]*upow[b];
          sb += B3mT[t4*CCH + c]*upow[b];
        }
        cA[t] = sa*LOG2E; cB[t] = sb; ++t;
      }
    cA[15] = 0.f; cB[15] = 0.f;
  }

  __syncthreads();

  float mrun = -INFINITY, srun = 0.f, a0 = 0.f, a1 = 0.f, a2 = 0.f;
  #pragma unroll 2
  for (int nn = 0; nn < TILE; ++nn) {
    const float4* pv = (const float4*)&wlds[mi][nn][0];
    const float4 p0 = pv[0], p1 = pv[1], p2 = pv[2], p3 = pv[3];
    const float4 xq = *(const float4*)&xt[nn][0];
    float laA = cA[0]*p0.x + cA[1]*p0.y + cA[2]*p0.z + cA[3]*p0.w
              + cA[4]*p1.x + cA[5]*p1.y + cA[6]*p1.z + cA[7]*p1.w;
    float laB = cA[8]*p2.x + cA[9]*p2.y + cA[10]*p2.z + cA[11]*p2.w
              + cA[12]*p3.x + cA[13]*p3.y + cA[14]*p3.z;
    float lbA = cB[0]*p0.x + cB[1]*p0.y + cB[2]*p0.z + cB[3]*p0.w
              + cB[4]*p1.x + cB[5]*p1.y + cB[6]*p1.z + cB[7]*p1.w;
    float lbB = cB[8]*p2.x + cB[9]*p2.y + cB[10]*p2.z + cB[11]*p2.w
              + cB[12]*p3.x + cB[13]*p3.y + cB[14]*p3.z;
    const float h2 = (laA + laB) * (lbA + lbB);   // h * log2e
    const float mnew = fmaxf(mrun, h2);
    const float scale = fast_exp2(mrun - mnew);
    const float e = fast_exp2(h2 - mnew);
    srun = fmaf(srun, scale, e);
    a0 = fmaf(a0, scale, e*xq.x);
    a1 = fmaf(a1, scale, e*xq.y);
    a2 = fmaf(a2, scale, e*xq.z);
    mrun = mnew;
  }
  const int idx = chunk*PAIR + m*CCH + c;
  Mp[idx] = mrun; Sp[idx] = srun;
  A0p[idx] = a0; A1p[idx] = a1; A2p[idx] = a2;
}

// ---------------------------------------------------------------------------
// k_fin (96 blocks x 256): merge chunk partials per (m,c), normalize,
// LDS-reduce 8 m-rows, 384 atomics/block into apart; last block (ticket)
// does the Wf contraction and writes out.
// ---------------------------------------------------------------------------
__global__ __launch_bounds__(256) void k_fin(
    const float* __restrict__ x,
    const float* __restrict__ Mp, const float* __restrict__ Sp,
    const float* __restrict__ A0p, const float* __restrict__ A1p,
    const float* __restrict__ A2p,
    const float* __restrict__ Wf,
    float* __restrict__ apart, unsigned int* __restrict__ ticket,
    float* __restrict__ out) {
  __shared__ float red2[2][3][CCH];
  __shared__ float red[CCH][6];
  __shared__ bool last;
  const int tid = threadIdx.x;
  const int ml = tid >> 7;
  const int c = tid & 127;

  float s0 = 0.f, s1 = 0.f, s2 = 0.f;
  #pragma unroll
  for (int j = 0; j < 4; ++j) {
    const int m = blockIdx.x*8 + ml*4 + j;
    const int gid = m*CCH + c;
    float m0 = Mp[0*PAIR + gid], m1 = Mp[1*PAIR + gid], m2 = Mp[2*PAIR + gid];
    float m3 = Mp[3*PAIR + gid], m4 = Mp[4*PAIR + gid], m5 = Mp[5*PAIR + gid];
    float M = fmaxf(fmaxf(fmaxf(m0, m1), fmaxf(m2, m3)), fmaxf(m4, m5));
    float W = 0.f, g0 = 0.f, g1 = 0.f, g2 = 0.f;
    {
      const float e0 = fast_exp2(m0 - M), e1 = fast_exp2(m1 - M);
      const float e2 = fast_exp2(m2 - M), e3 = fast_exp2(m3 - M);
      const float e4 = fast_exp2(m4 - M), e5 = fast_exp2(m5 - M);
      W = Sp[0*PAIR+gid]*e0 + Sp[1*PAIR+gid]*e1 + Sp[2*PAIR+gid]*e2
        + Sp[3*PAIR+gid]*e3 + Sp[4*PAIR+gid]*e4 + Sp[5*PAIR+gid]*e5;
      g0 = A0p[0*PAIR+gid]*e0 + A0p[1*PAIR+gid]*e1 + A0p[2*PAIR+gid]*e2
         + A0p[3*PAIR+gid]*e3 + A0p[4*PAIR+gid]*e4 + A0p[5*PAIR+gid]*e5;
      g1 = A1p[0*PAIR+gid]*e0 + A1p[1*PAIR+gid]*e1 + A1p[2*PAIR+gid]*e2
         + A1p[3*PAIR+gid]*e3 + A1p[4*PAIR+gid]*e4 + A1p[5*PAIR+gid]*e5;
      g2 = A2p[0*PAIR+gid]*e0 + A2p[1*PAIR+gid]*e1 + A2p[2*PAIR+gid]*e2
         + A2p[3*PAIR+gid]*e3 + A2p[4*PAIR+gid]*e4 + A2p[5*PAIR+gid]*e5;
    }
    const float inv = 1.f / W;
    s0 = fmaf(g0, inv, s0);
    s1 = fmaf(g1, inv, s1);
    s2 = fmaf(g2, inv, s2);
  }
  red2[ml][0][c] = s0; red2[ml][1][c] = s1; red2[ml][2][c] = s2;
  __syncthreads();
  for (int p = tid; p < NACC; p += 256) {
    const int i = p >> 7, cc = p & 127;
    atomicAdd(&apart[p], red2[0][i][cc] + red2[1][i][cc]);
  }
  __threadfence();
  __syncthreads();
  if (tid == 0) {
    const unsigned int old = atomicAdd(ticket, 1u);
    last = (old == FINB - 1);
  }
  __syncthreads();
  if (!last) return;
  __threadfence();

  if (tid < CCH) {
    const int cc = tid;
    const float a0 = __hip_atomic_load(&apart[cc],          __ATOMIC_RELAXED, __HIP_MEMORY_SCOPE_AGENT);
    const float a1 = __hip_atomic_load(&apart[CCH + cc],    __ATOMIC_RELAXED, __HIP_MEMORY_SCOPE_AGENT);
    const float a2 = __hip_atomic_load(&apart[2*CCH + cc],  __ATOMIC_RELAXED, __HIP_MEMORY_SCOPE_AGENT);
    const float w0 = Wf[cc], w1 = Wf[CCH + cc];
    red[cc][0] = w0*a0; red[cc][1] = w0*a1; red[cc][2] = w0*a2;
    red[cc][3] = w1*a0; red[cc][4] = w1*a1; red[cc][5] = w1*a2;
  }
  __syncthreads();
  if (tid < 6) {
    float s = 0.f;
    for (int k = 0; k < CCH; ++k) s += red[k][tid];
    out[3 + tid] = s;
  }
  if (tid < 3) out[tid] = x[tid];
}

// ---------------------------------------------------------------------------
extern "C" void kernel_launch(void* const* d_in, const int* in_sizes, int n_in,
                              void* d_out, int out_size, void* d_ws, size_t ws_size,
                              hipStream_t stream) {
  const float* x   = (const float*)d_in[0];
  const float* Wa1 = (const float*)d_in[1];
  const float* ba1 = (const float*)d_in[2];
  const float* Wb1 = (const float*)d_in[3];
  const float* bb1 = (const float*)d_in[4];
  const float* Wa2 = (const float*)d_in[5];
  const float* ba2 = (const float*)d_in[6];
  const float* Wb2 = (const float*)d_in[7];
  const float* bb2 = (const float*)d_in[8];
  const float* Wa3 = (const float*)d_in[9];
  const float* ba3 = (const float*)d_in[10];
  const float* Wb3 = (const float*)d_in[11];
  const float* bb3 = (const float*)d_in[12];
  const float* Wf  = (const float*)d_in[13];
  float* out = (float*)d_out;

  float* ws     = (float*)d_ws;
  float* norms  = ws;                      // 768
  float* C2m    = norms + NPTS;            // 128*36
  float* A3mT   = C2m   + CCH*NM4;         // 36*128
  float* B3mT   = A3mT  + NM4*CCH;         // 36*128
  float* Mp     = B3mT  + NM4*CCH;         // 6*98304
  float* Sp     = Mp    + NCHUNK*PAIR;     // 6*98304
  float* A0p    = Sp    + NCHUNK*PAIR;     // 6*98304
  float* A1p    = A0p   + NCHUNK*PAIR;     // 6*98304
  float* A2p    = A1p   + NCHUNK*PAIR;     // 6*98304
  float* apart  = A2p   + NCHUNK*PAIR;     // 384
  unsigned int* ticket = (unsigned int*)(apart + NACC);

  hipLaunchKernelGGL(k_fold12, dim3(CCH), dim3(128), 0, stream,
                     x, Wa1, ba1, Wb1, bb1, Wa2, ba2, Wb2, bb2,
                     norms, C2m, apart, ticket);
  hipLaunchKernelGGL(k_pre2, dim3(CCH), dim3(64), 0, stream,
                     Wa3, ba3, Wb3, bb3, C2m, A3mT, B3mT);
  hipLaunchKernelGGL(k_main, dim3(NPTS/2, NCHUNK), dim3(256), 0, stream,
                     x, norms, A3mT, B3mT, Mp, Sp, A0p, A1p, A2p);
  hipLaunchKernelGGL(k_fin, dim3(FINB), dim3(256), 0, stream,
                     x, Mp, Sp, A0p, A1p, A2p, Wf, apart, ticket, out);
}

// Round 9
// 172.298 us; speedup vs baseline: 1.4895x; 1.1345x over previous
//
#include <hip/hip_runtime.h>

#define NPTS 768
#define CCH  128
#define NM4  36    // 35 deg<=4 monomials in (d,u,v) + 1 pad
#define NM2  10    // deg<=2 monomials
#define TILE 128
#define NCHUNK 6   // one 128-tile of n per block
#define PAIR (NPTS*CCH)
#define NACC 384   // apart accumulator size (3 x 128)
#define FINB 96    // k_fin grid
#define LOG2E 1.4426950408889634f

__device__ __forceinline__ float fast_exp2(float x) {
  return __builtin_amdgcn_exp2f(x);   // v_exp_f32 (base-2)
}

// ---- monomial index helpers ------------------------------------------------
// (a,b,c) = (deg d, deg u, deg v), a outermost. Compile-time foldable in
// k_main's shallow unrolled nests; runtime-safe elsewhere (indexes LDS/global
// only, never private arrays — scratch-spill hazard, see R6/R7 notes).
__device__ __forceinline__ int t4i(int a, int b, int c) {
  int t = 0;
  for (int aa = 0; aa < a; ++aa) t += (5 - aa) * (6 - aa) / 2;
  for (int bb = 0; bb < b; ++bb) t += (5 - a - bb);
  return t + c;
}
__device__ __forceinline__ int t2i(int a, int b, int c) {
  int t = 0;
  for (int aa = 0; aa < a; ++aa) t += (3 - aa) * (4 - aa) / 2;
  for (int bb = 0; bb < b; ++bb) t += (3 - a - bb);
  return t + c;
}

// ---------------------------------------------------------------------------
// k_fold12 — unchanged from R8. NOTE: as the first kernel in the stream it
// absorbs a ~90 us fixed stall (harness ws-poison/restore drain; measured
// across R6-R8: first dispatch always ~90-110 us with VALUBusy ~0).
// ---------------------------------------------------------------------------
__global__ __launch_bounds__(128) void k_fold12(
    const float* __restrict__ x,
    const float* __restrict__ Wa1, const float* __restrict__ ba1,
    const float* __restrict__ Wb1, const float* __restrict__ bb1,
    const float* __restrict__ Wa2, const float* __restrict__ ba2,
    const float* __restrict__ Wb2, const float* __restrict__ bb2,
    float* __restrict__ norms, float* __restrict__ C2m,
    float* __restrict__ apart, unsigned int* __restrict__ ticket) {
  __shared__ float sA[128][NM2];
  __shared__ float sB[128][NM2];
  const int c = blockIdx.x;
  const int k = threadIdx.x;

  if (c < 6) {
    const int i = c*128 + k;
    const float p0 = x[3*i], p1 = x[3*i+1], p2 = x[3*i+2];
    norms[i] = sqrtf(p0*p0 + p1*p1 + p2*p2);
  }
  if (c == 6) {
    apart[k] = 0.f; apart[CCH + k] = 0.f; apart[2*CCH + k] = 0.f;
    if (k == 0) *ticket = 0u;
  }

  {
    const float A0 = Wa1[3*k], A1 = Wa1[3*k+1], A2c = Wa1[3*k+2], A3 = ba1[k];
    const float B0 = Wb1[3*k], B1 = Wb1[3*k+1], B2c = Wb1[3*k+2], B3 = bb1[k];
    const float g0 = A3*B3;              // 1
    const float g1 = A2c*B3 + A3*B2c;    // v
    const float g2 = A2c*B2c;            // v^2
    const float g3 = A1*B3 + A3*B1;      // u
    const float g4 = A1*B2c + A2c*B1;    // u v
    const float g5 = A1*B1;              // u^2
    const float g6 = A0*B3 + A3*B0;      // d
    const float g7 = A0*B2c + A2c*B0;    // d v
    const float g8 = A0*B1 + A1*B0;      // d u
    const float g9 = A0*B0;              // d^2
    const float wa = Wa2[c*CCH + k];
    const float wb = Wb2[c*CCH + k];
    sA[k][0] = wa*g0; sB[k][0] = wb*g0;
    sA[k][1] = wa*g1; sB[k][1] = wb*g1;
    sA[k][2] = wa*g2; sB[k][2] = wb*g2;
    sA[k][3] = wa*g3; sB[k][3] = wb*g3;
    sA[k][4] = wa*g4; sB[k][4] = wb*g4;
    sA[k][5] = wa*g5; sB[k][5] = wb*g5;
    sA[k][6] = wa*g6; sB[k][6] = wb*g6;
    sA[k][7] = wa*g7; sB[k][7] = wb*g7;
    sA[k][8] = wa*g8; sB[k][8] = wb*g8;
    sA[k][9] = wa*g9; sB[k][9] = wb*g9;
  }
  __syncthreads();

  for (int s = 64; s >= 1; s >>= 1) {
    if (k < s) {
      for (int t = 0; t < NM2; ++t) {
        sA[k][t] += sA[k+s][t];
        sB[k][t] += sB[k+s][t];
      }
    }
    __syncthreads();
  }
  if (k == 0) {
    sA[0][0] += ba2[c];
    sB[0][0] += bb2[c];
  }
  __syncthreads();

  if (k < 35) {
    int rem = k, a = 0;
    while (rem >= (5 - a)*(6 - a)/2) { rem -= (5 - a)*(6 - a)/2; ++a; }
    int b = 0;
    while (rem >= 5 - a - b) { rem -= 5 - a - b; ++b; }
    const int cc = rem;
    float s = 0.f;
    const int deg = a + b + cc;
    for (int a1 = 0; a1 <= a && a1 <= 2; ++a1)
      for (int b1 = 0; b1 <= b && b1 <= 2; ++b1)
        for (int c1 = 0; c1 <= cc && c1 <= 2; ++c1) {
          const int d1 = a1 + b1 + c1;
          if (d1 <= 2 && (deg - d1) <= 2)
            s += sA[0][t2i(a1, b1, c1)]
               * sB[0][t2i(a - a1, b - b1, cc - c1)];
        }
    C2m[c*NM4 + k] = s;
  }
  if (k == 35) C2m[c*NM4 + 35] = 0.f;
}

// ---------------------------------------------------------------------------
// k_pre2 (128 blocks x 64 thr): A3mT/B3mT = layer-3 fold, transposed (36x128).
// ---------------------------------------------------------------------------
__global__ void k_pre2(const float* __restrict__ Wa3, const float* __restrict__ ba3,
                       const float* __restrict__ Wb3, const float* __restrict__ bb3,
                       const float* __restrict__ C2m,
                       float* __restrict__ A3mT, float* __restrict__ B3mT) {
  const int c = blockIdx.x;
  const int j = threadIdx.x;
  if (j >= NM4) return;
  float sa = 0.f, sb = 0.f;
  if (j < 35) {
    for (int k = 0; k < CCH; ++k) {
      const float v = C2m[k*NM4 + j];
      sa += Wa3[c*CCH + k] * v;
      sb += Wb3[c*CCH + k] * v;
    }
    if (j == 0) { sa += ba3[c]; sb += bb3[c]; }
  }
  A3mT[j*CCH + c] = sa;
  B3mT[j*CCH + c] = sb;
}

// ---------------------------------------------------------------------------
// k_main: block = (m-pair, n-chunk of 128), 256 threads = 2 m-halves x 128 c.
// Horner-form bivariate poly in (d, v) — no psi tile, 3 KB LDS (broadcast
// reads, no bank conflicts). Chunk-4 online softmax in log2 domain.
// cA layout (i = deg d, j = deg v, i-major):
//   i=0: [0..4]  i=1: [5..8]  i=2: [9..11]  i=3: [12..13]  i=4: [14]
// ---------------------------------------------------------------------------
__global__ __launch_bounds__(256) void k_main(
    const float* __restrict__ x, const float* __restrict__ norms,
    const float* __restrict__ A3mT, const float* __restrict__ B3mT,
    float* __restrict__ Mp, float* __restrict__ Sp,
    float* __restrict__ A0p, float* __restrict__ A1p, float* __restrict__ A2p) {
  __shared__ float wd[2][TILE];                 // d per (m-half, n)
  __shared__ __align__(16) float4 xv[TILE];     // (v, x0, x1, x2) per n
  const int tid = threadIdx.x;
  const int mi = tid >> 7;
  const int c = tid & 127;
  const int m = blockIdx.x*2 + mi;
  const int chunk = blockIdx.y;

  const float u = norms[m];
  const float xm0 = x[3*m], xm1 = x[3*m+1], xm2 = x[3*m+2];

  // Stage d (per half) and (v,x) (shared) for this chunk's 128 n's.
  {
    const int n = chunk*TILE + c;
    const float v = norms[n];
    const float x0 = x[3*n], x1 = x[3*n+1], x2 = x[3*n+2];
    const float dot = xm0*x0 + xm1*x1 + xm2*x2;
    const float d2 = u*u + v*v - 2.f*dot;
    wd[mi][c] = (d2 > 0.f) ? sqrtf(d2) : 0.f;
    if (mi == 0) xv[c] = make_float4(v, x0, x1, x2);
  }

  // Fold u-powers into 15 per-channel coeffs; log2e folded into cA.
  float upow[5]; upow[0] = 1.f;
  #pragma unroll
  for (int b = 1; b < 5; ++b) upow[b] = upow[b-1]*u;
  float cA[15], cB[15];
  {
    int t = 0;
    #pragma unroll
    for (int i = 0; i <= 4; ++i)
      #pragma unroll
      for (int j = 0; i + j <= 4; ++j) {
        float sa = 0.f, sb = 0.f;
        #pragma unroll
        for (int b = 0; i + j + b <= 4; ++b) {
          const int t4 = t4i(i, b, j);   // (deg d, deg u, deg v)
          sa += A3mT[t4*CCH + c]*upow[b];
          sb += B3mT[t4*CCH + c]*upow[b];
        }
        cA[t] = sa*LOG2E; cB[t] = sb; ++t;
      }
  }

  __syncthreads();

  float mrun = -INFINITY, srun = 0.f, a0 = 0.f, a1 = 0.f, a2 = 0.f;
  for (int base = 0; base < TILE; base += 4) {
    float h[4];
    #pragma unroll
    for (int q = 0; q < 4; ++q) {
      const int nn = base + q;
      const float d = wd[mi][nn];
      const float v = xv[nn].x;
      float pa = fmaf(fmaf(fmaf(fmaf(cA[4], v, cA[3]), v, cA[2]), v, cA[1]), v, cA[0]);
      float qa = fmaf(fmaf(fmaf(cA[8], v, cA[7]), v, cA[6]), v, cA[5]);
      float ra = fmaf(fmaf(cA[11], v, cA[10]), v, cA[9]);
      float sa = fmaf(cA[13], v, cA[12]);
      const float la = fmaf(fmaf(fmaf(fmaf(cA[14], d, sa), d, ra), d, qa), d, pa);
      float pb = fmaf(fmaf(fmaf(fmaf(cB[4], v, cB[3]), v, cB[2]), v, cB[1]), v, cB[0]);
      float qb = fmaf(fmaf(fmaf(cB[8], v, cB[7]), v, cB[6]), v, cB[5]);
      float rb = fmaf(fmaf(cB[11], v, cB[10]), v, cB[9]);
      float sb = fmaf(cB[13], v, cB[12]);
      const float lb = fmaf(fmaf(fmaf(fmaf(cB[14], d, sb), d, rb), d, qb), d, pb);
      h[q] = la * lb;                     // h * log2e
    }
    const float m4 = fmaxf(fmaxf(h[0], h[1]), fmaxf(h[2], h[3]));
    const float mnew = fmaxf(mrun, m4);
    const float scale = fast_exp2(mrun - mnew);
    srun *= scale; a0 *= scale; a1 *= scale; a2 *= scale;
    #pragma unroll
    for (int q = 0; q < 4; ++q) {
      const float e = fast_exp2(h[q] - mnew);
      const float4 vx = xv[base + q];
      srun += e;
      a0 = fmaf(e, vx.y, a0);
      a1 = fmaf(e, vx.z, a1);
      a2 = fmaf(e, vx.w, a2);
    }
    mrun = mnew;
  }
  const int idx = chunk*PAIR + m*CCH + c;
  Mp[idx] = mrun; Sp[idx] = srun;
  A0p[idx] = a0; A1p[idx] = a1; A2p[idx] = a2;
}

// ---------------------------------------------------------------------------
// k_fin (96 blocks x 256): merge chunk partials per (m,c), normalize,
// LDS-reduce 8 m-rows, 384 atomics/block into apart; last block (ticket)
// does the Wf contraction and writes out.
// ---------------------------------------------------------------------------
__global__ __launch_bounds__(256) void k_fin(
    const float* __restrict__ x,
    const float* __restrict__ Mp, const float* __restrict__ Sp,
    const float* __restrict__ A0p, const float* __restrict__ A1p,
    const float* __restrict__ A2p,
    const float* __restrict__ Wf,
    float* __restrict__ apart, unsigned int* __restrict__ ticket,
    float* __restrict__ out) {
  __shared__ float red2[2][3][CCH];
  __shared__ float red[CCH][6];
  __shared__ bool last;
  const int tid = threadIdx.x;
  const int ml = tid >> 7;
  const int c = tid & 127;

  float s0 = 0.f, s1 = 0.f, s2 = 0.f;
  #pragma unroll
  for (int j = 0; j < 4; ++j) {
    const int m = blockIdx.x*8 + ml*4 + j;
    const int gid = m*CCH + c;
    float m0 = Mp[0*PAIR + gid], m1 = Mp[1*PAIR + gid], m2 = Mp[2*PAIR + gid];
    float m3 = Mp[3*PAIR + gid], m4 = Mp[4*PAIR + gid], m5 = Mp[5*PAIR + gid];
    float M = fmaxf(fmaxf(fmaxf(m0, m1), fmaxf(m2, m3)), fmaxf(m4, m5));
    float W = 0.f, g0 = 0.f, g1 = 0.f, g2 = 0.f;
    {
      const float e0 = fast_exp2(m0 - M), e1 = fast_exp2(m1 - M);
      const float e2 = fast_exp2(m2 - M), e3 = fast_exp2(m3 - M);
      const float e4 = fast_exp2(m4 - M), e5 = fast_exp2(m5 - M);
      W = Sp[0*PAIR+gid]*e0 + Sp[1*PAIR+gid]*e1 + Sp[2*PAIR+gid]*e2
        + Sp[3*PAIR+gid]*e3 + Sp[4*PAIR+gid]*e4 + Sp[5*PAIR+gid]*e5;
      g0 = A0p[0*PAIR+gid]*e0 + A0p[1*PAIR+gid]*e1 + A0p[2*PAIR+gid]*e2
         + A0p[3*PAIR+gid]*e3 + A0p[4*PAIR+gid]*e4 + A0p[5*PAIR+gid]*e5;
      g1 = A1p[0*PAIR+gid]*e0 + A1p[1*PAIR+gid]*e1 + A1p[2*PAIR+gid]*e2
         + A1p[3*PAIR+gid]*e3 + A1p[4*PAIR+gid]*e4 + A1p[5*PAIR+gid]*e5;
      g2 = A2p[0*PAIR+gid]*e0 + A2p[1*PAIR+gid]*e1 + A2p[2*PAIR+gid]*e2
         + A2p[3*PAIR+gid]*e3 + A2p[4*PAIR+gid]*e4 + A2p[5*PAIR+gid]*e5;
    }
    const float inv = 1.f / W;
    s0 = fmaf(g0, inv, s0);
    s1 = fmaf(g1, inv, s1);
    s2 = fmaf(g2, inv, s2);
  }
  red2[ml][0][c] = s0; red2[ml][1][c] = s1; red2[ml][2][c] = s2;
  __syncthreads();
  for (int p = tid; p < NACC; p += 256) {
    const int i = p >> 7, cc = p & 127;
    atomicAdd(&apart[p], red2[0][i][cc] + red2[1][i][cc]);
  }
  __threadfence();
  __syncthreads();
  if (tid == 0) {
    const unsigned int old = atomicAdd(ticket, 1u);
    last = (old == FINB - 1);
  }
  __syncthreads();
  if (!last) return;
  __threadfence();

  if (tid < CCH) {
    const int cc = tid;
    const float a0 = __hip_atomic_load(&apart[cc],          __ATOMIC_RELAXED, __HIP_MEMORY_SCOPE_AGENT);
    const float a1 = __hip_atomic_load(&apart[CCH + cc],    __ATOMIC_RELAXED, __HIP_MEMORY_SCOPE_AGENT);
    const float a2 = __hip_atomic_load(&apart[2*CCH + cc],  __ATOMIC_RELAXED, __HIP_MEMORY_SCOPE_AGENT);
    const float w0 = Wf[cc], w1 = Wf[CCH + cc];
    red[cc][0] = w0*a0; red[cc][1] = w0*a1; red[cc][2] = w0*a2;
    red[cc][3] = w1*a0; red[cc][4] = w1*a1; red[cc][5] = w1*a2;
  }
  __syncthreads();
  if (tid < 6) {
    float s = 0.f;
    for (int k = 0; k < CCH; ++k) s += red[k][tid];
    out[3 + tid] = s;
  }
  if (tid < 3) out[tid] = x[tid];
}

// ---------------------------------------------------------------------------
extern "C" void kernel_launch(void* const* d_in, const int* in_sizes, int n_in,
                              void* d_out, int out_size, void* d_ws, size_t ws_size,
                              hipStream_t stream) {
  const float* x   = (const float*)d_in[0];
  const float* Wa1 = (const float*)d_in[1];
  const float* ba1 = (const float*)d_in[2];
  const float* Wb1 = (const float*)d_in[3];
  const float* bb1 = (const float*)d_in[4];
  const float* Wa2 = (const float*)d_in[5];
  const float* ba2 = (const float*)d_in[6];
  const float* Wb2 = (const float*)d_in[7];
  const float* bb2 = (const float*)d_in[8];
  const float* Wa3 = (const float*)d_in[9];
  const float* ba3 = (const float*)d_in[10];
  const float* Wb3 = (const float*)d_in[11];
  const float* bb3 = (const float*)d_in[12];
  const float* Wf  = (const float*)d_in[13];
  float* out = (float*)d_out;

  float* ws     = (float*)d_ws;
  float* norms  = ws;                      // 768
  float* C2m    = norms + NPTS;            // 128*36
  float* A3mT   = C2m   + CCH*NM4;         // 36*128
  float* B3mT   = A3mT  + NM4*CCH;         // 36*128
  float* Mp     = B3mT  + NM4*CCH;         // 6*98304
  float* Sp     = Mp    + NCHUNK*PAIR;     // 6*98304
  float* A0p    = Sp    + NCHUNK*PAIR;     // 6*98304
  float* A1p    = A0p   + NCHUNK*PAIR;     // 6*98304
  float* A2p    = A1p   + NCHUNK*PAIR;     // 6*98304
  float* apart  = A2p   + NCHUNK*PAIR;     // 384
  unsigned int* ticket = (unsigned int*)(apart + NACC);

  hipLaunchKernelGGL(k_fold12, dim3(CCH), dim3(128), 0, stream,
                     x, Wa1, ba1, Wb1, bb1, Wa2, ba2, Wb2, bb2,
                     norms, C2m, apart, ticket);
  hipLaunchKernelGGL(k_pre2, dim3(CCH), dim3(64), 0, stream,
                     Wa3, ba3, Wb3, bb3, C2m, A3mT, B3mT);
  hipLaunchKernelGGL(k_main, dim3(NPTS/2, NCHUNK), dim3(256), 0, stream,
                     x, norms, A3mT, B3mT, Mp, Sp, A0p, A1p, A2p);
  hipLaunchKernelGGL(k_fin, dim3(FINB), dim3(256), 0, stream,
                     x, Mp, Sp, A0p, A1p, A2p, Wf, apart, ticket, out);
}

// Round 10
// 170.928 us; speedup vs baseline: 1.5014x; 1.0080x over previous
//
#include <hip/hip_runtime.h>

#define NPTS 768
#define CCH  128
#define NM4  36    // 35 deg<=4 monomials in (d,u,v) + 1 pad
#define NM2  10    // deg<=2 monomials
#define TILE 128
#define NCHUNK 6   // one 128-tile of n per block
#define PAIR (NPTS*CCH)
#define NACC 384   // apart accumulator size (3 x 128)
#define FINB 96    // k_fin grid
#define LOG2E 1.4426950408889634f

typedef float f2 __attribute__((ext_vector_type(2)));

__device__ __forceinline__ float fast_exp2(float x) {
  return __builtin_amdgcn_exp2f(x);   // v_exp_f32 (base-2)
}

// packed f32 fma: {x,y} lanes computed by one v_pk_fma_f32 (gfx90a+/CDNA4).
// R5 showed the compiler won't select packed-f32 from vector ops; emit direct.
#define PK_FMA_INIT(dst, a, b, c) \
  asm("v_pk_fma_f32 %0, %1, %2, %3" : "=v"(dst) : "v"(a), "v"(b), "v"(c))
#define PK_FMA_ACC(dst, b, c) \
  asm("v_pk_fma_f32 %0, %0, %1, %2" : "+v"(dst) : "v"(b), "v"(c))

// ---- monomial index helpers ------------------------------------------------
// (a,b,c) = (deg d, deg u, deg v), a outermost. Compile-time foldable in
// k_main's shallow unrolled nests; runtime-safe elsewhere (indexes LDS/global
// only, never private arrays — scratch-spill hazard, see R6/R7 notes).
__device__ __forceinline__ int t4i(int a, int b, int c) {
  int t = 0;
  for (int aa = 0; aa < a; ++aa) t += (5 - aa) * (6 - aa) / 2;
  for (int bb = 0; bb < b; ++bb) t += (5 - a - bb);
  return t + c;
}
__device__ __forceinline__ int t2i(int a, int b, int c) {
  int t = 0;
  for (int aa = 0; aa < a; ++aa) t += (3 - aa) * (4 - aa) / 2;
  for (int bb = 0; bb < b; ++bb) t += (3 - a - bb);
  return t + c;
}

// ---------------------------------------------------------------------------
// k_fold12 — unchanged from R8/R9. NOTE: as the first kernel in the stream it
// absorbs a ~90 us fixed stall (harness ws-poison/restore drain; measured
// across R6-R9: first dispatch window always ~90-110 us with VALUBusy ~0).
// ---------------------------------------------------------------------------
__global__ __launch_bounds__(128) void k_fold12(
    const float* __restrict__ x,
    const float* __restrict__ Wa1, const float* __restrict__ ba1,
    const float* __restrict__ Wb1, const float* __restrict__ bb1,
    const float* __restrict__ Wa2, const float* __restrict__ ba2,
    const float* __restrict__ Wb2, const float* __restrict__ bb2,
    float* __restrict__ norms, float* __restrict__ C2m,
    float* __restrict__ apart, unsigned int* __restrict__ ticket) {
  __shared__ float sA[128][NM2];
  __shared__ float sB[128][NM2];
  const int c = blockIdx.x;
  const int k = threadIdx.x;

  if (c < 6) {
    const int i = c*128 + k;
    const float p0 = x[3*i], p1 = x[3*i+1], p2 = x[3*i+2];
    norms[i] = sqrtf(p0*p0 + p1*p1 + p2*p2);
  }
  if (c == 6) {
    apart[k] = 0.f; apart[CCH + k] = 0.f; apart[2*CCH + k] = 0.f;
    if (k == 0) *ticket = 0u;
  }

  {
    const float A0 = Wa1[3*k], A1 = Wa1[3*k+1], A2c = Wa1[3*k+2], A3 = ba1[k];
    const float B0 = Wb1[3*k], B1 = Wb1[3*k+1], B2c = Wb1[3*k+2], B3 = bb1[k];
    const float g0 = A3*B3;              // 1
    const float g1 = A2c*B3 + A3*B2c;    // v
    const float g2 = A2c*B2c;            // v^2
    const float g3 = A1*B3 + A3*B1;      // u
    const float g4 = A1*B2c + A2c*B1;    // u v
    const float g5 = A1*B1;              // u^2
    const float g6 = A0*B3 + A3*B0;      // d
    const float g7 = A0*B2c + A2c*B0;    // d v
    const float g8 = A0*B1 + A1*B0;      // d u
    const float g9 = A0*B0;              // d^2
    const float wa = Wa2[c*CCH + k];
    const float wb = Wb2[c*CCH + k];
    sA[k][0] = wa*g0; sB[k][0] = wb*g0;
    sA[k][1] = wa*g1; sB[k][1] = wb*g1;
    sA[k][2] = wa*g2; sB[k][2] = wb*g2;
    sA[k][3] = wa*g3; sB[k][3] = wb*g3;
    sA[k][4] = wa*g4; sB[k][4] = wb*g4;
    sA[k][5] = wa*g5; sB[k][5] = wb*g5;
    sA[k][6] = wa*g6; sB[k][6] = wb*g6;
    sA[k][7] = wa*g7; sB[k][7] = wb*g7;
    sA[k][8] = wa*g8; sB[k][8] = wb*g8;
    sA[k][9] = wa*g9; sB[k][9] = wb*g9;
  }
  __syncthreads();

  for (int s = 64; s >= 1; s >>= 1) {
    if (k < s) {
      for (int t = 0; t < NM2; ++t) {
        sA[k][t] += sA[k+s][t];
        sB[k][t] += sB[k+s][t];
      }
    }
    __syncthreads();
  }
  if (k == 0) {
    sA[0][0] += ba2[c];
    sB[0][0] += bb2[c];
  }
  __syncthreads();

  if (k < 35) {
    int rem = k, a = 0;
    while (rem >= (5 - a)*(6 - a)/2) { rem -= (5 - a)*(6 - a)/2; ++a; }
    int b = 0;
    while (rem >= 5 - a - b) { rem -= 5 - a - b; ++b; }
    const int cc = rem;
    float s = 0.f;
    const int deg = a + b + cc;
    for (int a1 = 0; a1 <= a && a1 <= 2; ++a1)
      for (int b1 = 0; b1 <= b && b1 <= 2; ++b1)
        for (int c1 = 0; c1 <= cc && c1 <= 2; ++c1) {
          const int d1 = a1 + b1 + c1;
          if (d1 <= 2 && (deg - d1) <= 2)
            s += sA[0][t2i(a1, b1, c1)]
               * sB[0][t2i(a - a1, b - b1, cc - c1)];
        }
    C2m[c*NM4 + k] = s;
  }
  if (k == 35) C2m[c*NM4 + 35] = 0.f;
}

// ---------------------------------------------------------------------------
// k_pre2 (128 blocks x 64 thr): A3mT/B3mT = layer-3 fold, transposed (36x128).
// ---------------------------------------------------------------------------
__global__ void k_pre2(const float* __restrict__ Wa3, const float* __restrict__ ba3,
                       const float* __restrict__ Wb3, const float* __restrict__ bb3,
                       const float* __restrict__ C2m,
                       float* __restrict__ A3mT, float* __restrict__ B3mT) {
  const int c = blockIdx.x;
  const int j = threadIdx.x;
  if (j >= NM4) return;
  float sa = 0.f, sb = 0.f;
  if (j < 35) {
    for (int k = 0; k < CCH; ++k) {
      const float v = C2m[k*NM4 + j];
      sa += Wa3[c*CCH + k] * v;
      sb += Wb3[c*CCH + k] * v;
    }
    if (j == 0) { sa += ba3[c]; sb += bb3[c]; }
  }
  A3mT[j*CCH + c] = sa;
  B3mT[j*CCH + c] = sb;
}

// ---------------------------------------------------------------------------
// k_main: block = (m-pair, n-chunk of 128), 256 threads = 2 m-halves x 128 c.
// Packed-f32 Horner: {la, lb} chains evaluated together in v_pk_fma_f32
// (coeffs packed {cA,cB}; d/v staged duplicated {d,d}/{v,v} in LDS for
// broadcast ds_read_b64). Chunk-4 online softmax in log2 domain.
// cA layout (i = deg d, j = deg v, i-major):
//   i=0: [0..4]  i=1: [5..8]  i=2: [9..11]  i=3: [12..13]  i=4: [14]
// ---------------------------------------------------------------------------
__global__ __launch_bounds__(256) void k_main(
    const float* __restrict__ x, const float* __restrict__ norms,
    const float* __restrict__ A3mT, const float* __restrict__ B3mT,
    float* __restrict__ Mp, float* __restrict__ Sp,
    float* __restrict__ A0p, float* __restrict__ A1p, float* __restrict__ A2p) {
  __shared__ f2 wdp[2][TILE];                   // {d, d} per (m-half, n)
  __shared__ f2 vvp[TILE];                      // {v, v} per n
  __shared__ __align__(16) float4 xt[TILE];     // (x0, x1, x2, 0) per n
  const int tid = threadIdx.x;
  const int mi = tid >> 7;
  const int c = tid & 127;
  const int m = blockIdx.x*2 + mi;
  const int chunk = blockIdx.y;

  const float u = norms[m];
  const float xm0 = x[3*m], xm1 = x[3*m+1], xm2 = x[3*m+2];

  // Stage d (per half) and v/x (shared) for this chunk's 128 n's.
  {
    const int n = chunk*TILE + c;
    const float v = norms[n];
    const float x0 = x[3*n], x1 = x[3*n+1], x2 = x[3*n+2];
    const float dot = xm0*x0 + xm1*x1 + xm2*x2;
    const float d2 = u*u + v*v - 2.f*dot;
    const float d = (d2 > 0.f) ? sqrtf(d2) : 0.f;
    f2 dd; dd.x = d; dd.y = d;
    wdp[mi][c] = dd;
    if (mi == 0) {
      f2 vv; vv.x = v; vv.y = v;
      vvp[c] = vv;
      xt[c] = make_float4(x0, x1, x2, 0.f);
    }
  }

  // Fold u-powers into 15 packed per-channel coeffs {cA*log2e, cB}.
  float upow[5]; upow[0] = 1.f;
  #pragma unroll
  for (int b = 1; b < 5; ++b) upow[b] = upow[b-1]*u;
  f2 cAB[15];
  {
    int t = 0;
    #pragma unroll
    for (int i = 0; i <= 4; ++i)
      #pragma unroll
      for (int j = 0; i + j <= 4; ++j) {
        float sa = 0.f, sb = 0.f;
        #pragma unroll
        for (int b = 0; i + j + b <= 4; ++b) {
          const int t4 = t4i(i, b, j);   // (deg d, deg u, deg v)
          sa += A3mT[t4*CCH + c]*upow[b];
          sb += B3mT[t4*CCH + c]*upow[b];
        }
        f2 cc; cc.x = sa*LOG2E; cc.y = sb;
        cAB[t] = cc; ++t;
      }
  }

  __syncthreads();

  float mrun = -INFINITY, srun = 0.f, a0 = 0.f, a1 = 0.f, a2 = 0.f;
  for (int base = 0; base < TILE; base += 4) {
    float h[4];
    #pragma unroll
    for (int q = 0; q < 4; ++q) {
      const int nn = base + q;
      const f2 dd = wdp[mi][nn];
      const f2 vv = vvp[nn];
      f2 p, qq, r, s, l;
      PK_FMA_INIT(p,  cAB[4],  vv, cAB[3]);   // v-chains (Horner in v)
      PK_FMA_ACC (p,  vv, cAB[2]);
      PK_FMA_ACC (p,  vv, cAB[1]);
      PK_FMA_ACC (p,  vv, cAB[0]);
      PK_FMA_INIT(qq, cAB[8],  vv, cAB[7]);
      PK_FMA_ACC (qq, vv, cAB[6]);
      PK_FMA_ACC (qq, vv, cAB[5]);
      PK_FMA_INIT(r,  cAB[11], vv, cAB[10]);
      PK_FMA_ACC (r,  vv, cAB[9]);
      PK_FMA_INIT(s,  cAB[13], vv, cAB[12]);
      PK_FMA_INIT(l,  cAB[14], dd, s);        // d-chain (Horner in d)
      PK_FMA_ACC (l,  dd, r);
      PK_FMA_ACC (l,  dd, qq);
      PK_FMA_ACC (l,  dd, p);
      h[q] = l.x * l.y;                       // (la*log2e) * lb
    }
    const float m4 = fmaxf(fmaxf(h[0], h[1]), fmaxf(h[2], h[3]));
    const float mnew = fmaxf(mrun, m4);
    const float scale = fast_exp2(mrun - mnew);
    srun *= scale; a0 *= scale; a1 *= scale; a2 *= scale;
    #pragma unroll
    for (int q = 0; q < 4; ++q) {
      const float e = fast_exp2(h[q] - mnew);
      const float4 vx = xt[base + q];
      srun += e;
      a0 = fmaf(e, vx.x, a0);
      a1 = fmaf(e, vx.y, a1);
      a2 = fmaf(e, vx.z, a2);
    }
    mrun = mnew;
  }
  const int idx = chunk*PAIR + m*CCH + c;
  Mp[idx] = mrun; Sp[idx] = srun;
  A0p[idx] = a0; A1p[idx] = a1; A2p[idx] = a2;
}

// ---------------------------------------------------------------------------
// k_fin (96 blocks x 256): merge chunk partials per (m,c), normalize,
// LDS-reduce 8 m-rows, 384 atomics/block into apart; last block (ticket)
// does the Wf contraction and writes out.
// ---------------------------------------------------------------------------
__global__ __launch_bounds__(256) void k_fin(
    const float* __restrict__ x,
    const float* __restrict__ Mp, const float* __restrict__ Sp,
    const float* __restrict__ A0p, const float* __restrict__ A1p,
    const float* __restrict__ A2p,
    const float* __restrict__ Wf,
    float* __restrict__ apart, unsigned int* __restrict__ ticket,
    float* __restrict__ out) {
  __shared__ float red2[2][3][CCH];
  __shared__ float red[CCH][6];
  __shared__ bool last;
  const int tid = threadIdx.x;
  const int ml = tid >> 7;
  const int c = tid & 127;

  float s0 = 0.f, s1 = 0.f, s2 = 0.f;
  #pragma unroll
  for (int j = 0; j < 4; ++j) {
    const int m = blockIdx.x*8 + ml*4 + j;
    const int gid = m*CCH + c;
    float m0 = Mp[0*PAIR + gid], m1 = Mp[1*PAIR + gid], m2 = Mp[2*PAIR + gid];
    float m3 = Mp[3*PAIR + gid], m4 = Mp[4*PAIR + gid], m5 = Mp[5*PAIR + gid];
    float M = fmaxf(fmaxf(fmaxf(m0, m1), fmaxf(m2, m3)), fmaxf(m4, m5));
    float W = 0.f, g0 = 0.f, g1 = 0.f, g2 = 0.f;
    {
      const float e0 = fast_exp2(m0 - M), e1 = fast_exp2(m1 - M);
      const float e2 = fast_exp2(m2 - M), e3 = fast_exp2(m3 - M);
      const float e4 = fast_exp2(m4 - M), e5 = fast_exp2(m5 - M);
      W = Sp[0*PAIR+gid]*e0 + Sp[1*PAIR+gid]*e1 + Sp[2*PAIR+gid]*e2
        + Sp[3*PAIR+gid]*e3 + Sp[4*PAIR+gid]*e4 + Sp[5*PAIR+gid]*e5;
      g0 = A0p[0*PAIR+gid]*e0 + A0p[1*PAIR+gid]*e1 + A0p[2*PAIR+gid]*e2
         + A0p[3*PAIR+gid]*e3 + A0p[4*PAIR+gid]*e4 + A0p[5*PAIR+gid]*e5;
      g1 = A1p[0*PAIR+gid]*e0 + A1p[1*PAIR+gid]*e1 + A1p[2*PAIR+gid]*e2
         + A1p[3*PAIR+gid]*e3 + A1p[4*PAIR+gid]*e4 + A1p[5*PAIR+gid]*e5;
      g2 = A2p[0*PAIR+gid]*e0 + A2p[1*PAIR+gid]*e1 + A2p[2*PAIR+gid]*e2
         + A2p[3*PAIR+gid]*e3 + A2p[4*PAIR+gid]*e4 + A2p[5*PAIR+gid]*e5;
    }
    const float inv = 1.f / W;
    s0 = fmaf(g0, inv, s0);
    s1 = fmaf(g1, inv, s1);
    s2 = fmaf(g2, inv, s2);
  }
  red2[ml][0][c] = s0; red2[ml][1][c] = s1; red2[ml][2][c] = s2;
  __syncthreads();
  for (int p = tid; p < NACC; p += 256) {
    const int i = p >> 7, cc = p & 127;
    atomicAdd(&apart[p], red2[0][i][cc] + red2[1][i][cc]);
  }
  __threadfence();
  __syncthreads();
  if (tid == 0) {
    const unsigned int old = atomicAdd(ticket, 1u);
    last = (old == FINB - 1);
  }
  __syncthreads();
  if (!last) return;
  __threadfence();

  if (tid < CCH) {
    const int cc = tid;
    const float a0 = __hip_atomic_load(&apart[cc],          __ATOMIC_RELAXED, __HIP_MEMORY_SCOPE_AGENT);
    const float a1 = __hip_atomic_load(&apart[CCH + cc],    __ATOMIC_RELAXED, __HIP_MEMORY_SCOPE_AGENT);
    const float a2 = __hip_atomic_load(&apart[2*CCH + cc],  __ATOMIC_RELAXED, __HIP_MEMORY_SCOPE_AGENT);
    const float w0 = Wf[cc], w1 = Wf[CCH + cc];
    red[cc][0] = w0*a0; red[cc][1] = w0*a1; red[cc][2] = w0*a2;
    red[cc][3] = w1*a0; red[cc][4] = w1*a1; red[cc][5] = w1*a2;
  }
  __syncthreads();
  if (tid < 6) {
    float s = 0.f;
    for (int k = 0; k < CCH; ++k) s += red[k][tid];
    out[3 + tid] = s;
  }
  if (tid < 3) out[tid] = x[tid];
}

// ---------------------------------------------------------------------------
extern "C" void kernel_launch(void* const* d_in, const int* in_sizes, int n_in,
                              void* d_out, int out_size, void* d_ws, size_t ws_size,
                              hipStream_t stream) {
  const float* x   = (const float*)d_in[0];
  const float* Wa1 = (const float*)d_in[1];
  const float* ba1 = (const float*)d_in[2];
  const float* Wb1 = (const float*)d_in[3];
  const float* bb1 = (const float*)d_in[4];
  const float* Wa2 = (const float*)d_in[5];
  const float* ba2 = (const float*)d_in[6];
  const float* Wb2 = (const float*)d_in[7];
  const float* bb2 = (const float*)d_in[8];
  const float* Wa3 = (const float*)d_in[9];
  const float* ba3 = (const float*)d_in[10];
  const float* Wb3 = (const float*)d_in[11];
  const float* bb3 = (const float*)d_in[12];
  const float* Wf  = (const float*)d_in[13];
  float* out = (float*)d_out;

  float* ws     = (float*)d_ws;
  float* norms  = ws;                      // 768
  float* C2m    = norms + NPTS;            // 128*36
  float* A3mT   = C2m   + CCH*NM4;         // 36*128
  float* B3mT   = A3mT  + NM4*CCH;         // 36*128
  float* Mp     = B3mT  + NM4*CCH;         // 6*98304
  float* Sp     = Mp    + NCHUNK*PAIR;     // 6*98304
  float* A0p    = Sp    + NCHUNK*PAIR;     // 6*98304
  float* A1p    = A0p   + NCHUNK*PAIR;     // 6*98304
  float* A2p    = A1p   + NCHUNK*PAIR;     // 6*98304
  float* apart  = A2p   + NCHUNK*PAIR;     // 384
  unsigned int* ticket = (unsigned int*)(apart + NACC);

  hipLaunchKernelGGL(k_fold12, dim3(CCH), dim3(128), 0, stream,
                     x, Wa1, ba1, Wb1, bb1, Wa2, ba2, Wb2, bb2,
                     norms, C2m, apart, ticket);
  hipLaunchKernelGGL(k_pre2, dim3(CCH), dim3(64), 0, stream,
                     Wa3, ba3, Wb3, bb3, C2m, A3mT, B3mT);
  hipLaunchKernelGGL(k_main, dim3(NPTS/2, NCHUNK), dim3(256), 0, stream,
                     x, norms, A3mT, B3mT, Mp, Sp, A0p, A1p, A2p);
  hipLaunchKernelGGL(k_fin, dim3(FINB), dim3(256), 0, stream,
                     x, Mp, Sp, A0p, A1p, A2p, Wf, apart, ticket, out);
}

// Round 11
// 170.349 us; speedup vs baseline: 1.5065x; 1.0034x over previous
//
#include <hip/hip_runtime.h>

#define NPTS 768
#define CCH  128
#define NM4  36    // 35 deg<=4 monomials in (d,u,v) + 1 pad
#define NM2  10    // deg<=2 monomials
#define TILE 128
#define NCHUNK 6   // one 128-tile of n per block
#define PAIR (NPTS*CCH)
#define NACC 384   // apart accumulator size (3 x 128)
#define FINB 96    // k_fin grid
#define LOG2E 1.4426950408889634f

typedef float f2 __attribute__((ext_vector_type(2)));

__device__ __forceinline__ float fast_exp2(float x) {
  return __builtin_amdgcn_exp2f(x);   // v_exp_f32 (base-2)
}

// Packed f32 fma via compiler selection (VOP3P v_pk_fma_f32 on <2 x float>).
// R10 showed inline-asm pk forces ~2 v_mov marshalling per op (VALUBusy
// unchanged); the builtin leaves pair placement to regalloc.
__device__ __forceinline__ f2 pk_fma(f2 a, f2 b, f2 c) {
  return __builtin_elementwise_fma(a, b, c);
}

// ---- monomial index helpers ------------------------------------------------
// (a,b,c) = (deg d, deg u, deg v), a outermost. Compile-time foldable in
// k_main's shallow unrolled nests; runtime-safe elsewhere (indexes LDS/global
// only, never private arrays — scratch-spill hazard, see R6/R7 notes).
__device__ __forceinline__ int t4i(int a, int b, int c) {
  int t = 0;
  for (int aa = 0; aa < a; ++aa) t += (5 - aa) * (6 - aa) / 2;
  for (int bb = 0; bb < b; ++bb) t += (5 - a - bb);
  return t + c;
}
__device__ __forceinline__ int t2i(int a, int b, int c) {
  int t = 0;
  for (int aa = 0; aa < a; ++aa) t += (3 - aa) * (4 - aa) / 2;
  for (int bb = 0; bb < b; ++bb) t += (3 - a - bb);
  return t + c;
}

// ---------------------------------------------------------------------------
// k_fold12 — unchanged from R8/R9. NOTE: the ~100 us of non-k_main time is a
// fixed harness-side stream cost (ws re-poison + input restore before the
// graph; invariant across R6-R10 at 3-7 kernel configs) — not optimizable.
// ---------------------------------------------------------------------------
__global__ __launch_bounds__(128) void k_fold12(
    const float* __restrict__ x,
    const float* __restrict__ Wa1, const float* __restrict__ ba1,
    const float* __restrict__ Wb1, const float* __restrict__ bb1,
    const float* __restrict__ Wa2, const float* __restrict__ ba2,
    const float* __restrict__ Wb2, const float* __restrict__ bb2,
    float* __restrict__ norms, float* __restrict__ C2m,
    float* __restrict__ apart, unsigned int* __restrict__ ticket) {
  __shared__ float sA[128][NM2];
  __shared__ float sB[128][NM2];
  const int c = blockIdx.x;
  const int k = threadIdx.x;

  if (c < 6) {
    const int i = c*128 + k;
    const float p0 = x[3*i], p1 = x[3*i+1], p2 = x[3*i+2];
    norms[i] = sqrtf(p0*p0 + p1*p1 + p2*p2);
  }
  if (c == 6) {
    apart[k] = 0.f; apart[CCH + k] = 0.f; apart[2*CCH + k] = 0.f;
    if (k == 0) *ticket = 0u;
  }

  {
    const float A0 = Wa1[3*k], A1 = Wa1[3*k+1], A2c = Wa1[3*k+2], A3 = ba1[k];
    const float B0 = Wb1[3*k], B1 = Wb1[3*k+1], B2c = Wb1[3*k+2], B3 = bb1[k];
    const float g0 = A3*B3;              // 1
    const float g1 = A2c*B3 + A3*B2c;    // v
    const float g2 = A2c*B2c;            // v^2
    const float g3 = A1*B3 + A3*B1;      // u
    const float g4 = A1*B2c + A2c*B1;    // u v
    const float g5 = A1*B1;              // u^2
    const float g6 = A0*B3 + A3*B0;      // d
    const float g7 = A0*B2c + A2c*B0;    // d v
    const float g8 = A0*B1 + A1*B0;      // d u
    const float g9 = A0*B0;              // d^2
    const float wa = Wa2[c*CCH + k];
    const float wb = Wb2[c*CCH + k];
    sA[k][0] = wa*g0; sB[k][0] = wb*g0;
    sA[k][1] = wa*g1; sB[k][1] = wb*g1;
    sA[k][2] = wa*g2; sB[k][2] = wb*g2;
    sA[k][3] = wa*g3; sB[k][3] = wb*g3;
    sA[k][4] = wa*g4; sB[k][4] = wb*g4;
    sA[k][5] = wa*g5; sB[k][5] = wb*g5;
    sA[k][6] = wa*g6; sB[k][6] = wb*g6;
    sA[k][7] = wa*g7; sB[k][7] = wb*g7;
    sA[k][8] = wa*g8; sB[k][8] = wb*g8;
    sA[k][9] = wa*g9; sB[k][9] = wb*g9;
  }
  __syncthreads();

  for (int s = 64; s >= 1; s >>= 1) {
    if (k < s) {
      for (int t = 0; t < NM2; ++t) {
        sA[k][t] += sA[k+s][t];
        sB[k][t] += sB[k+s][t];
      }
    }
    __syncthreads();
  }
  if (k == 0) {
    sA[0][0] += ba2[c];
    sB[0][0] += bb2[c];
  }
  __syncthreads();

  if (k < 35) {
    int rem = k, a = 0;
    while (rem >= (5 - a)*(6 - a)/2) { rem -= (5 - a)*(6 - a)/2; ++a; }
    int b = 0;
    while (rem >= 5 - a - b) { rem -= 5 - a - b; ++b; }
    const int cc = rem;
    float s = 0.f;
    const int deg = a + b + cc;
    for (int a1 = 0; a1 <= a && a1 <= 2; ++a1)
      for (int b1 = 0; b1 <= b && b1 <= 2; ++b1)
        for (int c1 = 0; c1 <= cc && c1 <= 2; ++c1) {
          const int d1 = a1 + b1 + c1;
          if (d1 <= 2 && (deg - d1) <= 2)
            s += sA[0][t2i(a1, b1, c1)]
               * sB[0][t2i(a - a1, b - b1, cc - c1)];
        }
    C2m[c*NM4 + k] = s;
  }
  if (k == 35) C2m[c*NM4 + 35] = 0.f;
}

// ---------------------------------------------------------------------------
// k_pre2 (128 blocks x 64 thr): A3mT/B3mT = layer-3 fold, transposed (36x128).
// ---------------------------------------------------------------------------
__global__ void k_pre2(const float* __restrict__ Wa3, const float* __restrict__ ba3,
                       const float* __restrict__ Wb3, const float* __restrict__ bb3,
                       const float* __restrict__ C2m,
                       float* __restrict__ A3mT, float* __restrict__ B3mT) {
  const int c = blockIdx.x;
  const int j = threadIdx.x;
  if (j >= NM4) return;
  float sa = 0.f, sb = 0.f;
  if (j < 35) {
    for (int k = 0; k < CCH; ++k) {
      const float v = C2m[k*NM4 + j];
      sa += Wa3[c*CCH + k] * v;
      sb += Wb3[c*CCH + k] * v;
    }
    if (j == 0) { sa += ba3[c]; sb += bb3[c]; }
  }
  A3mT[j*CCH + c] = sa;
  B3mT[j*CCH + c] = sb;
}

// ---------------------------------------------------------------------------
// k_main: block = (m-pair, n-chunk of 128), 256 threads = 2 m-halves x 128 c.
// Packed-f32 Horner via <2 x float> elementwise-fma (backend-selected
// v_pk_fma_f32, no marshalling). Packed accumulators {a0,a1}, {a2,srun}.
// Chunk-4 online softmax in log2 domain.
// cAB layout (i = deg d, j = deg v, i-major):
//   i=0: [0..4]  i=1: [5..8]  i=2: [9..11]  i=3: [12..13]  i=4: [14]
// ---------------------------------------------------------------------------
__global__ __launch_bounds__(256) void k_main(
    const float* __restrict__ x, const float* __restrict__ norms,
    const float* __restrict__ A3mT, const float* __restrict__ B3mT,
    float* __restrict__ Mp, float* __restrict__ Sp,
    float* __restrict__ A0p, float* __restrict__ A1p, float* __restrict__ A2p) {
  __shared__ f2 wdp[2][TILE];                   // {d, d} per (m-half, n)
  __shared__ f2 vvp[TILE];                      // {v, v} per n
  __shared__ __align__(16) float4 xt[TILE];     // (x0, x1, x2, 1.0) per n
  const int tid = threadIdx.x;
  const int mi = tid >> 7;
  const int c = tid & 127;
  const int m = blockIdx.x*2 + mi;
  const int chunk = blockIdx.y;

  const float u = norms[m];
  const float xm0 = x[3*m], xm1 = x[3*m+1], xm2 = x[3*m+2];

  // Stage d (per half) and v/x (shared) for this chunk's 128 n's.
  {
    const int n = chunk*TILE + c;
    const float v = norms[n];
    const float x0 = x[3*n], x1 = x[3*n+1], x2 = x[3*n+2];
    const float dot = xm0*x0 + xm1*x1 + xm2*x2;
    const float d2 = u*u + v*v - 2.f*dot;
    const float d = (d2 > 0.f) ? sqrtf(d2) : 0.f;
    f2 dd; dd.x = d; dd.y = d;
    wdp[mi][c] = dd;
    if (mi == 0) {
      f2 vv; vv.x = v; vv.y = v;
      vvp[c] = vv;
      xt[c] = make_float4(x0, x1, x2, 1.0f);
    }
  }

  // Fold u-powers into 15 packed per-channel coeffs {cA*log2e, cB}.
  float upow[5]; upow[0] = 1.f;
  #pragma unroll
  for (int b = 1; b < 5; ++b) upow[b] = upow[b-1]*u;
  f2 cAB[15];
  {
    int t = 0;
    #pragma unroll
    for (int i = 0; i <= 4; ++i)
      #pragma unroll
      for (int j = 0; i + j <= 4; ++j) {
        float sa = 0.f, sb = 0.f;
        #pragma unroll
        for (int b = 0; i + j + b <= 4; ++b) {
          const int t4 = t4i(i, b, j);   // (deg d, deg u, deg v)
          sa += A3mT[t4*CCH + c]*upow[b];
          sb += B3mT[t4*CCH + c]*upow[b];
        }
        f2 cc; cc.x = sa*LOG2E; cc.y = sb;
        cAB[t] = cc; ++t;
      }
  }

  __syncthreads();

  float mrun = -INFINITY;
  f2 acc01; acc01.x = 0.f; acc01.y = 0.f;   // {a0, a1}
  f2 acc2s; acc2s.x = 0.f; acc2s.y = 0.f;   // {a2, srun}
  for (int base = 0; base < TILE; base += 4) {
    float h[4];
    #pragma unroll
    for (int q = 0; q < 4; ++q) {
      const int nn = base + q;
      const f2 dd = wdp[mi][nn];
      const f2 vv = vvp[nn];
      f2 p = pk_fma(cAB[4], vv, cAB[3]);     // v-chains (Horner in v)
      p = pk_fma(p, vv, cAB[2]);
      p = pk_fma(p, vv, cAB[1]);
      p = pk_fma(p, vv, cAB[0]);
      f2 qq = pk_fma(cAB[8], vv, cAB[7]);
      qq = pk_fma(qq, vv, cAB[6]);
      qq = pk_fma(qq, vv, cAB[5]);
      f2 r = pk_fma(cAB[11], vv, cAB[10]);
      r = pk_fma(r, vv, cAB[9]);
      const f2 s = pk_fma(cAB[13], vv, cAB[12]);
      f2 l = pk_fma(cAB[14], dd, s);         // d-chain (Horner in d)
      l = pk_fma(l, dd, r);
      l = pk_fma(l, dd, qq);
      l = pk_fma(l, dd, p);
      h[q] = l.x * l.y;                      // (la*log2e) * lb
    }
    const float m4 = fmaxf(fmaxf(h[0], h[1]), fmaxf(h[2], h[3]));
    const float mnew = fmaxf(mrun, m4);
    const float scale = fast_exp2(mrun - mnew);
    f2 sc; sc.x = scale; sc.y = scale;
    acc01 *= sc;
    acc2s *= sc;
    #pragma unroll
    for (int q = 0; q < 4; ++q) {
      const float e = fast_exp2(h[q] - mnew);
      f2 ee; ee.x = e; ee.y = e;
      const float4 vx = xt[base + q];        // {x0, x1, x2, 1.0}
      f2 x01; x01.x = vx.x; x01.y = vx.y;
      f2 x2o; x2o.x = vx.z; x2o.y = vx.w;
      acc01 = pk_fma(ee, x01, acc01);
      acc2s = pk_fma(ee, x2o, acc2s);        // {a2 += e*x2, srun += e}
    }
    mrun = mnew;
  }
  const int idx = chunk*PAIR + m*CCH + c;
  Mp[idx] = mrun; Sp[idx] = acc2s.y;
  A0p[idx] = acc01.x; A1p[idx] = acc01.y; A2p[idx] = acc2s.x;
}

// ---------------------------------------------------------------------------
// k_fin (96 blocks x 256): merge chunk partials per (m,c), normalize,
// LDS-reduce 8 m-rows, 384 atomics/block into apart; last block (ticket)
// does the Wf contraction and writes out.
// ---------------------------------------------------------------------------
__global__ __launch_bounds__(256) void k_fin(
    const float* __restrict__ x,
    const float* __restrict__ Mp, const float* __restrict__ Sp,
    const float* __restrict__ A0p, const float* __restrict__ A1p,
    const float* __restrict__ A2p,
    const float* __restrict__ Wf,
    float* __restrict__ apart, unsigned int* __restrict__ ticket,
    float* __restrict__ out) {
  __shared__ float red2[2][3][CCH];
  __shared__ float red[CCH][6];
  __shared__ bool last;
  const int tid = threadIdx.x;
  const int ml = tid >> 7;
  const int c = tid & 127;

  float s0 = 0.f, s1 = 0.f, s2 = 0.f;
  #pragma unroll
  for (int j = 0; j < 4; ++j) {
    const int m = blockIdx.x*8 + ml*4 + j;
    const int gid = m*CCH + c;
    float m0 = Mp[0*PAIR + gid], m1 = Mp[1*PAIR + gid], m2 = Mp[2*PAIR + gid];
    float m3 = Mp[3*PAIR + gid], m4 = Mp[4*PAIR + gid], m5 = Mp[5*PAIR + gid];
    float M = fmaxf(fmaxf(fmaxf(m0, m1), fmaxf(m2, m3)), fmaxf(m4, m5));
    float W = 0.f, g0 = 0.f, g1 = 0.f, g2 = 0.f;
    {
      const float e0 = fast_exp2(m0 - M), e1 = fast_exp2(m1 - M);
      const float e2 = fast_exp2(m2 - M), e3 = fast_exp2(m3 - M);
      const float e4 = fast_exp2(m4 - M), e5 = fast_exp2(m5 - M);
      W = Sp[0*PAIR+gid]*e0 + Sp[1*PAIR+gid]*e1 + Sp[2*PAIR+gid]*e2
        + Sp[3*PAIR+gid]*e3 + Sp[4*PAIR+gid]*e4 + Sp[5*PAIR+gid]*e5;
      g0 = A0p[0*PAIR+gid]*e0 + A0p[1*PAIR+gid]*e1 + A0p[2*PAIR+gid]*e2
         + A0p[3*PAIR+gid]*e3 + A0p[4*PAIR+gid]*e4 + A0p[5*PAIR+gid]*e5;
      g1 = A1p[0*PAIR+gid]*e0 + A1p[1*PAIR+gid]*e1 + A1p[2*PAIR+gid]*e2
         + A1p[3*PAIR+gid]*e3 + A1p[4*PAIR+gid]*e4 + A1p[5*PAIR+gid]*e5;
      g2 = A2p[0*PAIR+gid]*e0 + A2p[1*PAIR+gid]*e1 + A2p[2*PAIR+gid]*e2
         + A2p[3*PAIR+gid]*e3 + A2p[4*PAIR+gid]*e4 + A2p[5*PAIR+gid]*e5;
    }
    const float inv = 1.f / W;
    s0 = fmaf(g0, inv, s0);
    s1 = fmaf(g1, inv, s1);
    s2 = fmaf(g2, inv, s2);
  }
  red2[ml][0][c] = s0; red2[ml][1][c] = s1; red2[ml][2][c] = s2;
  __syncthreads();
  for (int p = tid; p < NACC; p += 256) {
    const int i = p >> 7, cc = p & 127;
    atomicAdd(&apart[p], red2[0][i][cc] + red2[1][i][cc]);
  }
  __threadfence();
  __syncthreads();
  if (tid == 0) {
    const unsigned int old = atomicAdd(ticket, 1u);
    last = (old == FINB - 1);
  }
  __syncthreads();
  if (!last) return;
  __threadfence();

  if (tid < CCH) {
    const int cc = tid;
    const float a0 = __hip_atomic_load(&apart[cc],          __ATOMIC_RELAXED, __HIP_MEMORY_SCOPE_AGENT);
    const float a1 = __hip_atomic_load(&apart[CCH + cc],    __ATOMIC_RELAXED, __HIP_MEMORY_SCOPE_AGENT);
    const float a2 = __hip_atomic_load(&apart[2*CCH + cc],  __ATOMIC_RELAXED, __HIP_MEMORY_SCOPE_AGENT);
    const float w0 = Wf[cc], w1 = Wf[CCH + cc];
    red[cc][0] = w0*a0; red[cc][1] = w0*a1; red[cc][2] = w0*a2;
    red[cc][3] = w1*a0; red[cc][4] = w1*a1; red[cc][5] = w1*a2;
  }
  __syncthreads();
  if (tid < 6) {
    float s = 0.f;
    for (int k = 0; k < CCH; ++k) s += red[k][tid];
    out[3 + tid] = s;
  }
  if (tid < 3) out[tid] = x[tid];
}

// ---------------------------------------------------------------------------
extern "C" void kernel_launch(void* const* d_in, const int* in_sizes, int n_in,
                              void* d_out, int out_size, void* d_ws, size_t ws_size,
                              hipStream_t stream) {
  const float* x   = (const float*)d_in[0];
  const float* Wa1 = (const float*)d_in[1];
  const float* ba1 = (const float*)d_in[2];
  const float* Wb1 = (const float*)d_in[3];
  const float* bb1 = (const float*)d_in[4];
  const float* Wa2 = (const float*)d_in[5];
  const float* ba2 = (const float*)d_in[6];
  const float* Wb2 = (const float*)d_in[7];
  const float* bb2 = (const float*)d_in[8];
  const float* Wa3 = (const float*)d_in[9];
  const float* ba3 = (const float*)d_in[10];
  const float* Wb3 = (const float*)d_in[11];
  const float* bb3 = (const float*)d_in[12];
  const float* Wf  = (const float*)d_in[13];
  float* out = (float*)d_out;

  float* ws     = (float*)d_ws;
  float* norms  = ws;                      // 768
  float* C2m    = norms + NPTS;            // 128*36
  float* A3mT   = C2m   + CCH*NM4;         // 36*128
  float* B3mT   = A3mT  + NM4*CCH;         // 36*128
  float* Mp     = B3mT  + NM4*CCH;         // 6*98304
  float* Sp     = Mp    + NCHUNK*PAIR;     // 6*98304
  float* A0p    = Sp    + NCHUNK*PAIR;     // 6*98304
  float* A1p    = A0p   + NCHUNK*PAIR;     // 6*98304
  float* A2p    = A1p   + NCHUNK*PAIR;     // 6*98304
  float* apart  = A2p   + NCHUNK*PAIR;     // 384
  unsigned int* ticket = (unsigned int*)(apart + NACC);

  hipLaunchKernelGGL(k_fold12, dim3(CCH), dim3(128), 0, stream,
                     x, Wa1, ba1, Wb1, bb1, Wa2, ba2, Wb2, bb2,
                     norms, C2m, apart, ticket);
  hipLaunchKernelGGL(k_pre2, dim3(CCH), dim3(64), 0, stream,
                     Wa3, ba3, Wb3, bb3, C2m, A3mT, B3mT);
  hipLaunchKernelGGL(k_main, dim3(NPTS/2, NCHUNK), dim3(256), 0, stream,
                     x, norms, A3mT, B3mT, Mp, Sp, A0p, A1p, A2p);
  hipLaunchKernelGGL(k_fin, dim3(FINB), dim3(256), 0, stream,
                     x, Mp, Sp, A0p, A1p, A2p, Wf, apart, ticket, out);
}

// Round 12
// 169.086 us; speedup vs baseline: 1.5178x; 1.0075x over previous
//
#include <hip/hip_runtime.h>

#define NPTS 768
#define CCH  128
#define NM4  36    // 35 deg<=4 monomials in (d,u,v) + 1 pad
#define NM2  10    // deg<=2 monomials
#define TILE 128
#define NCHUNK 6   // one 128-tile of n per block
#define PAIR (NPTS*CCH)
#define NACC 384   // apart accumulator size (3 x 128)
#define FINB 96    // k_fin grid
#define LOG2E 1.4426950408889634f

typedef float f2 __attribute__((ext_vector_type(2)));

__device__ __forceinline__ float fast_exp2(float x) {
  return __builtin_amdgcn_exp2f(x);   // v_exp_f32 (base-2)
}

// ---- monomial index helpers ------------------------------------------------
// (a,b,c) = (deg d, deg u, deg v), a outermost. Compile-time foldable in
// k_main's shallow unrolled nests; runtime-safe elsewhere (indexes LDS/global
// only, never private arrays — scratch-spill hazard, see R6/R7 notes).
__device__ __forceinline__ int t4i(int a, int b, int c) {
  int t = 0;
  for (int aa = 0; aa < a; ++aa) t += (5 - aa) * (6 - aa) / 2;
  for (int bb = 0; bb < b; ++bb) t += (5 - a - bb);
  return t + c;
}
__device__ __forceinline__ int t2i(int a, int b, int c) {
  int t = 0;
  for (int aa = 0; aa < a; ++aa) t += (3 - aa) * (4 - aa) / 2;
  for (int bb = 0; bb < b; ++bb) t += (3 - a - bb);
  return t + c;
}

// ---------------------------------------------------------------------------
// k_fold12 — layer-1/2 fold (LDS tree-reduce, no private arrays). The ~100 us
// of non-kernel time per replay is harness-side stream work (ws/out 0xAA
// poison + input restore, SDMA — not visible as dispatches); invariant
// across R6-R11 kernel configs.
// ---------------------------------------------------------------------------
__global__ __launch_bounds__(128) void k_fold12(
    const float* __restrict__ x,
    const float* __restrict__ Wa1, const float* __restrict__ ba1,
    const float* __restrict__ Wb1, const float* __restrict__ bb1,
    const float* __restrict__ Wa2, const float* __restrict__ ba2,
    const float* __restrict__ Wb2, const float* __restrict__ bb2,
    float* __restrict__ norms, float* __restrict__ C2m,
    float* __restrict__ apart, unsigned int* __restrict__ ticket) {
  __shared__ float sA[128][NM2];
  __shared__ float sB[128][NM2];
  const int c = blockIdx.x;
  const int k = threadIdx.x;

  if (c < 6) {
    const int i = c*128 + k;
    const float p0 = x[3*i], p1 = x[3*i+1], p2 = x[3*i+2];
    norms[i] = sqrtf(p0*p0 + p1*p1 + p2*p2);
  }
  if (c == 6) {
    apart[k] = 0.f; apart[CCH + k] = 0.f; apart[2*CCH + k] = 0.f;
    if (k == 0) *ticket = 0u;
  }

  {
    const float A0 = Wa1[3*k], A1 = Wa1[3*k+1], A2c = Wa1[3*k+2], A3 = ba1[k];
    const float B0 = Wb1[3*k], B1 = Wb1[3*k+1], B2c = Wb1[3*k+2], B3 = bb1[k];
    const float g0 = A3*B3;              // 1
    const float g1 = A2c*B3 + A3*B2c;    // v
    const float g2 = A2c*B2c;            // v^2
    const float g3 = A1*B3 + A3*B1;      // u
    const float g4 = A1*B2c + A2c*B1;    // u v
    const float g5 = A1*B1;              // u^2
    const float g6 = A0*B3 + A3*B0;      // d
    const float g7 = A0*B2c + A2c*B0;    // d v
    const float g8 = A0*B1 + A1*B0;      // d u
    const float g9 = A0*B0;              // d^2
    const float wa = Wa2[c*CCH + k];
    const float wb = Wb2[c*CCH + k];
    sA[k][0] = wa*g0; sB[k][0] = wb*g0;
    sA[k][1] = wa*g1; sB[k][1] = wb*g1;
    sA[k][2] = wa*g2; sB[k][2] = wb*g2;
    sA[k][3] = wa*g3; sB[k][3] = wb*g3;
    sA[k][4] = wa*g4; sB[k][4] = wb*g4;
    sA[k][5] = wa*g5; sB[k][5] = wb*g5;
    sA[k][6] = wa*g6; sB[k][6] = wb*g6;
    sA[k][7] = wa*g7; sB[k][7] = wb*g7;
    sA[k][8] = wa*g8; sB[k][8] = wb*g8;
    sA[k][9] = wa*g9; sB[k][9] = wb*g9;
  }
  __syncthreads();

  for (int s = 64; s >= 1; s >>= 1) {
    if (k < s) {
      for (int t = 0; t < NM2; ++t) {
        sA[k][t] += sA[k+s][t];
        sB[k][t] += sB[k+s][t];
      }
    }
    __syncthreads();
  }
  if (k == 0) {
    sA[0][0] += ba2[c];
    sB[0][0] += bb2[c];
  }
  __syncthreads();

  if (k < 35) {
    int rem = k, a = 0;
    while (rem >= (5 - a)*(6 - a)/2) { rem -= (5 - a)*(6 - a)/2; ++a; }
    int b = 0;
    while (rem >= 5 - a - b) { rem -= 5 - a - b; ++b; }
    const int cc = rem;
    float s = 0.f;
    const int deg = a + b + cc;
    for (int a1 = 0; a1 <= a && a1 <= 2; ++a1)
      for (int b1 = 0; b1 <= b && b1 <= 2; ++b1)
        for (int c1 = 0; c1 <= cc && c1 <= 2; ++c1) {
          const int d1 = a1 + b1 + c1;
          if (d1 <= 2 && (deg - d1) <= 2)
            s += sA[0][t2i(a1, b1, c1)]
               * sB[0][t2i(a - a1, b - b1, cc - c1)];
        }
    C2m[c*NM4 + k] = s;
  }
  if (k == 35) C2m[c*NM4 + 35] = 0.f;
}

// ---------------------------------------------------------------------------
// k_pre2 (128 blocks x 64 thr): A3mT/B3mT = layer-3 fold, transposed (36x128).
// ---------------------------------------------------------------------------
__global__ void k_pre2(const float* __restrict__ Wa3, const float* __restrict__ ba3,
                       const float* __restrict__ Wb3, const float* __restrict__ bb3,
                       const float* __restrict__ C2m,
                       float* __restrict__ A3mT, float* __restrict__ B3mT) {
  const int c = blockIdx.x;
  const int j = threadIdx.x;
  if (j >= NM4) return;
  float sa = 0.f, sb = 0.f;
  if (j < 35) {
    for (int k = 0; k < CCH; ++k) {
      const float v = C2m[k*NM4 + j];
      sa += Wa3[c*CCH + k] * v;
      sb += Wb3[c*CCH + k] * v;
    }
    if (j == 0) { sa += ba3[c]; sb += bb3[c]; }
  }
  A3mT[j*CCH + c] = sa;
  B3mT[j*CCH + c] = sb;
}

// ---------------------------------------------------------------------------
// k_main: block = (m-pair, n-chunk of 128), 256 threads = 2 m-halves x 128 c.
// Scalar Horner bivariate poly in (d, v) (R9-proven: packed-f32 attempts in
// R10/R11 were neutral — toolchain won't select clean v_pk_fma_f32).
// {d,v} packed per (m-half, n) -> one ds_read_b64; x staged as float4.
// Chunk-8 online softmax in log2 domain (1 rescale per 8 n).
// cA layout (i = deg d, j = deg v, i-major):
//   i=0: [0..4]  i=1: [5..8]  i=2: [9..11]  i=3: [12..13]  i=4: [14]
// ---------------------------------------------------------------------------
__global__ __launch_bounds__(256) void k_main(
    const float* __restrict__ x, const float* __restrict__ norms,
    const float* __restrict__ A3mT, const float* __restrict__ B3mT,
    float* __restrict__ Mp, float* __restrict__ Sp,
    float* __restrict__ A0p, float* __restrict__ A1p, float* __restrict__ A2p) {
  __shared__ f2 wdv[2][TILE];                   // {d, v} per (m-half, n)
  __shared__ __align__(16) float4 xt[TILE];     // (x0, x1, x2, 1) per n
  const int tid = threadIdx.x;
  const int mi = tid >> 7;
  const int c = tid & 127;
  const int m = blockIdx.x*2 + mi;
  const int chunk = blockIdx.y;

  const float u = norms[m];
  const float xm0 = x[3*m], xm1 = x[3*m+1], xm2 = x[3*m+2];

  // Stage {d,v} (per half) and x (shared) for this chunk's 128 n's.
  {
    const int n = chunk*TILE + c;
    const float v = norms[n];
    const float x0 = x[3*n], x1 = x[3*n+1], x2 = x[3*n+2];
    const float dot = xm0*x0 + xm1*x1 + xm2*x2;
    const float d2 = u*u + v*v - 2.f*dot;
    const float d = (d2 > 0.f) ? sqrtf(d2) : 0.f;
    f2 dv; dv.x = d; dv.y = v;
    wdv[mi][c] = dv;
    if (mi == 0) xt[c] = make_float4(x0, x1, x2, 1.0f);
  }

  // Fold u-powers into 15 per-channel coeffs; log2e folded into cA.
  float upow[5]; upow[0] = 1.f;
  #pragma unroll
  for (int b = 1; b < 5; ++b) upow[b] = upow[b-1]*u;
  float cA[15], cB[15];
  {
    int t = 0;
    #pragma unroll
    for (int i = 0; i <= 4; ++i)
      #pragma unroll
      for (int j = 0; i + j <= 4; ++j) {
        float sa = 0.f, sb = 0.f;
        #pragma unroll
        for (int b = 0; i + j + b <= 4; ++b) {
          const int t4 = t4i(i, b, j);   // (deg d, deg u, deg v)
          sa += A3mT[t4*CCH + c]*upow[b];
          sb += B3mT[t4*CCH + c]*upow[b];
        }
        cA[t] = sa*LOG2E; cB[t] = sb; ++t;
      }
  }

  __syncthreads();

  float mrun = -INFINITY, srun = 0.f, a0 = 0.f, a1 = 0.f, a2 = 0.f;
  for (int base = 0; base < TILE; base += 8) {
    float h[8];
    #pragma unroll
    for (int q = 0; q < 8; ++q) {
      const f2 dv = wdv[mi][base + q];
      const float d = dv.x;
      const float v = dv.y;
      float pa = fmaf(fmaf(fmaf(fmaf(cA[4], v, cA[3]), v, cA[2]), v, cA[1]), v, cA[0]);
      float qa = fmaf(fmaf(fmaf(cA[8], v, cA[7]), v, cA[6]), v, cA[5]);
      float ra = fmaf(fmaf(cA[11], v, cA[10]), v, cA[9]);
      float sa = fmaf(cA[13], v, cA[12]);
      const float la = fmaf(fmaf(fmaf(fmaf(cA[14], d, sa), d, ra), d, qa), d, pa);
      float pb = fmaf(fmaf(fmaf(fmaf(cB[4], v, cB[3]), v, cB[2]), v, cB[1]), v, cB[0]);
      float qb = fmaf(fmaf(fmaf(cB[8], v, cB[7]), v, cB[6]), v, cB[5]);
      float rb = fmaf(fmaf(cB[11], v, cB[10]), v, cB[9]);
      float sb = fmaf(cB[13], v, cB[12]);
      const float lb = fmaf(fmaf(fmaf(fmaf(cB[14], d, sb), d, rb), d, qb), d, pb);
      h[q] = la * lb;                     // h * log2e
    }
    const float m01 = fmaxf(h[0], h[1]), m23 = fmaxf(h[2], h[3]);
    const float m45 = fmaxf(h[4], h[5]), m67 = fmaxf(h[6], h[7]);
    const float m8 = fmaxf(fmaxf(m01, m23), fmaxf(m45, m67));
    const float mnew = fmaxf(mrun, m8);
    const float scale = fast_exp2(mrun - mnew);
    srun *= scale; a0 *= scale; a1 *= scale; a2 *= scale;
    #pragma unroll
    for (int q = 0; q < 8; ++q) {
      const float e = fast_exp2(h[q] - mnew);
      const float4 vx = xt[base + q];
      srun += e;
      a0 = fmaf(e, vx.x, a0);
      a1 = fmaf(e, vx.y, a1);
      a2 = fmaf(e, vx.z, a2);
    }
    mrun = mnew;
  }
  const int idx = chunk*PAIR + m*CCH + c;
  Mp[idx] = mrun; Sp[idx] = srun;
  A0p[idx] = a0; A1p[idx] = a1; A2p[idx] = a2;
}

// ---------------------------------------------------------------------------
// k_fin (96 blocks x 256): merge chunk partials per (m,c), normalize,
// LDS-reduce 8 m-rows, 384 atomics/block into apart; last block (ticket)
// does the Wf contraction and writes out.
// ---------------------------------------------------------------------------
__global__ __launch_bounds__(256) void k_fin(
    const float* __restrict__ x,
    const float* __restrict__ Mp, const float* __restrict__ Sp,
    const float* __restrict__ A0p, const float* __restrict__ A1p,
    const float* __restrict__ A2p,
    const float* __restrict__ Wf,
    float* __restrict__ apart, unsigned int* __restrict__ ticket,
    float* __restrict__ out) {
  __shared__ float red2[2][3][CCH];
  __shared__ float red[CCH][6];
  __shared__ bool last;
  const int tid = threadIdx.x;
  const int ml = tid >> 7;
  const int c = tid & 127;

  float s0 = 0.f, s1 = 0.f, s2 = 0.f;
  #pragma unroll
  for (int j = 0; j < 4; ++j) {
    const int m = blockIdx.x*8 + ml*4 + j;
    const int gid = m*CCH + c;
    float m0 = Mp[0*PAIR + gid], m1 = Mp[1*PAIR + gid], m2 = Mp[2*PAIR + gid];
    float m3 = Mp[3*PAIR + gid], m4 = Mp[4*PAIR + gid], m5 = Mp[5*PAIR + gid];
    float M = fmaxf(fmaxf(fmaxf(m0, m1), fmaxf(m2, m3)), fmaxf(m4, m5));
    float W = 0.f, g0 = 0.f, g1 = 0.f, g2 = 0.f;
    {
      const float e0 = fast_exp2(m0 - M), e1 = fast_exp2(m1 - M);
      const float e2 = fast_exp2(m2 - M), e3 = fast_exp2(m3 - M);
      const float e4 = fast_exp2(m4 - M), e5 = fast_exp2(m5 - M);
      W = Sp[0*PAIR+gid]*e0 + Sp[1*PAIR+gid]*e1 + Sp[2*PAIR+gid]*e2
        + Sp[3*PAIR+gid]*e3 + Sp[4*PAIR+gid]*e4 + Sp[5*PAIR+gid]*e5;
      g0 = A0p[0*PAIR+gid]*e0 + A0p[1*PAIR+gid]*e1 + A0p[2*PAIR+gid]*e2
         + A0p[3*PAIR+gid]*e3 + A0p[4*PAIR+gid]*e4 + A0p[5*PAIR+gid]*e5;
      g1 = A1p[0*PAIR+gid]*e0 + A1p[1*PAIR+gid]*e1 + A1p[2*PAIR+gid]*e2
         + A1p[3*PAIR+gid]*e3 + A1p[4*PAIR+gid]*e4 + A1p[5*PAIR+gid]*e5;
      g2 = A2p[0*PAIR+gid]*e0 + A2p[1*PAIR+gid]*e1 + A2p[2*PAIR+gid]*e2
         + A2p[3*PAIR+gid]*e3 + A2p[4*PAIR+gid]*e4 + A2p[5*PAIR+gid]*e5;
    }
    const float inv = 1.f / W;
    s0 = fmaf(g0, inv, s0);
    s1 = fmaf(g1, inv, s1);
    s2 = fmaf(g2, inv, s2);
  }
  red2[ml][0][c] = s0; red2[ml][1][c] = s1; red2[ml][2][c] = s2;
  __syncthreads();
  for (int p = tid; p < NACC; p += 256) {
    const int i = p >> 7, cc = p & 127;
    atomicAdd(&apart[p], red2[0][i][cc] + red2[1][i][cc]);
  }
  __threadfence();
  __syncthreads();
  if (tid == 0) {
    const unsigned int old = atomicAdd(ticket, 1u);
    last = (old == FINB - 1);
  }
  __syncthreads();
  if (!last) return;
  __threadfence();

  if (tid < CCH) {
    const int cc = tid;
    const float a0 = __hip_atomic_load(&apart[cc],          __ATOMIC_RELAXED, __HIP_MEMORY_SCOPE_AGENT);
    const float a1 = __hip_atomic_load(&apart[CCH + cc],    __ATOMIC_RELAXED, __HIP_MEMORY_SCOPE_AGENT);
    const float a2 = __hip_atomic_load(&apart[2*CCH + cc],  __ATOMIC_RELAXED, __HIP_MEMORY_SCOPE_AGENT);
    const float w0 = Wf[cc], w1 = Wf[CCH + cc];
    red[cc][0] = w0*a0; red[cc][1] = w0*a1; red[cc][2] = w0*a2;
    red[cc][3] = w1*a0; red[cc][4] = w1*a1; red[cc][5] = w1*a2;
  }
  __syncthreads();
  if (tid < 6) {
    float s = 0.f;
    for (int k = 0; k < CCH; ++k) s += red[k][tid];
    out[3 + tid] = s;
  }
  if (tid < 3) out[tid] = x[tid];
}

// ---------------------------------------------------------------------------
extern "C" void kernel_launch(void* const* d_in, const int* in_sizes, int n_in,
                              void* d_out, int out_size, void* d_ws, size_t ws_size,
                              hipStream_t stream) {
  const float* x   = (const float*)d_in[0];
  const float* Wa1 = (const float*)d_in[1];
  const float* ba1 = (const float*)d_in[2];
  const float* Wb1 = (const float*)d_in[3];
  const float* bb1 = (const float*)d_in[4];
  const float* Wa2 = (const float*)d_in[5];
  const float* ba2 = (const float*)d_in[6];
  const float* Wb2 = (const float*)d_in[7];
  const float* bb2 = (const float*)d_in[8];
  const float* Wa3 = (const float*)d_in[9];
  const float* ba3 = (const float*)d_in[10];
  const float* Wb3 = (const float*)d_in[11];
  const float* bb3 = (const float*)d_in[12];
  const float* Wf  = (const float*)d_in[13];
  float* out = (float*)d_out;

  float* ws     = (float*)d_ws;
  float* norms  = ws;                      // 768
  float* C2m    = norms + NPTS;            // 128*36
  float* A3mT   = C2m   + CCH*NM4;         // 36*128
  float* B3mT   = A3mT  + NM4*CCH;         // 36*128
  float* Mp     = B3mT  + NM4*CCH;         // 6*98304
  float* Sp     = Mp    + NCHUNK*PAIR;     // 6*98304
  float* A0p    = Sp    + NCHUNK*PAIR;     // 6*98304
  float* A1p    = A0p   + NCHUNK*PAIR;     // 6*98304
  float* A2p    = A1p   + NCHUNK*PAIR;     // 6*98304
  float* apart  = A2p   + NCHUNK*PAIR;     // 384
  unsigned int* ticket = (unsigned int*)(apart + NACC);

  hipLaunchKernelGGL(k_fold12, dim3(CCH), dim3(128), 0, stream,
                     x, Wa1, ba1, Wb1, bb1, Wa2, ba2, Wb2, bb2,
                     norms, C2m, apart, ticket);
  hipLaunchKernelGGL(k_pre2, dim3(CCH), dim3(64), 0, stream,
                     Wa3, ba3, Wb3, bb3, C2m, A3mT, B3mT);
  hipLaunchKernelGGL(k_main, dim3(NPTS/2, NCHUNK), dim3(256), 0, stream,
                     x, norms, A3mT, B3mT, Mp, Sp, A0p, A1p, A2p);
  hipLaunchKernelGGL(k_fin, dim3(FINB), dim3(256), 0, stream,
                     x, Mp, Sp, A0p, A1p, A2p, Wf, apart, ticket, out);
}